// Round 1
// baseline (1486.382 us; speedup 1.0000x reference)
//
#include <hip/hip_runtime.h>
#include <hip/hip_bf16.h>
#include <cstddef>

#define N_NODES 2048
#define E_EDGES 131072
#define IN_DIM  512
#define HID     2048
#define NCLS    16

#define BM 128
#define BN 128
#define BK 16

// ---------------------------------------------------------------------------
// Build dense adjacency counts A[dst, src] and per-dst degree counts.
// Adds of +1.0f are exact in fp32 and order-independent -> deterministic.
// ---------------------------------------------------------------------------
__global__ void build_adj_kernel(const int* __restrict__ src, const int* __restrict__ dst,
                                 float* __restrict__ adj, float* __restrict__ cnt) {
    int e = blockIdx.x * blockDim.x + threadIdx.x;
    if (e < E_EDGES) {
        int s = src[e], d = dst[e];
        atomicAdd(&adj[(size_t)d * N_NODES + s], 1.0f);
        atomicAdd(&cnt[d], 1.0f);
    }
}

__global__ void rscale_kernel(const float* __restrict__ cnt, float* __restrict__ rscale) {
    int i = blockIdx.x * blockDim.x + threadIdx.x;
    if (i < N_NODES) rscale[i] = 1.0f / fmaxf(cnt[i], 1.0f);
}

// ---------------------------------------------------------------------------
// Generic fp32 tiled GEMM:
//   C[M,N] = (A1[M,K1] @ B1[K1,N]) + (K2 ? A2[M,K2] @ B2[K2,N] : 0)
//            (then * rscale[m] if rscale) (then + bias[n] if bias) (then relu)
// Leading dims: A's ld == its K, B/C ld == N. All dims divide tile sizes.
// 256 threads, 8x8 per thread, interleaved (stride-16) thread->element map so
// LDS reads are broadcast (A) / 16-consecutive-bank (B) -> conflict-light.
// ---------------------------------------------------------------------------
__global__ __launch_bounds__(256) void gemm_f32(
    const float* __restrict__ A1, const float* __restrict__ B1, int K1,
    const float* __restrict__ A2, const float* __restrict__ B2, int K2,
    const float* __restrict__ bias, const float* __restrict__ rscale,
    float* __restrict__ C, int M, int N, int doRelu)
{
    __shared__ float As[BK][BM + 4];
    __shared__ float Bs[BK][BN + 4];

    const int tid = threadIdx.x;
    const int tx = tid & 15;   // column group (0..15)
    const int ty = tid >> 4;   // row group    (0..15)
    const int bm = blockIdx.y * BM;
    const int bn = blockIdx.x * BN;

    float acc[8][8];
#pragma unroll
    for (int i = 0; i < 8; ++i)
#pragma unroll
        for (int j = 0; j < 8; ++j) acc[i][j] = 0.0f;

#pragma unroll 1
    for (int pass = 0; pass < 2; ++pass) {
        const float* Ap = pass ? A2 : A1;
        const float* Bp = pass ? B2 : B1;
        const int    Kp = pass ? K2 : K1;
        if (Kp == 0) continue;

#pragma unroll 1
        for (int k0 = 0; k0 < Kp; k0 += BK) {
            __syncthreads();   // protect LDS from previous iteration's readers
            // ---- load A tile (BM x BK), store transposed As[k][m] ----
#pragma unroll
            for (int vv = 0; vv < 2; ++vv) {
                int v   = tid + vv * 256;     // 0..511
                int row = v >> 2;             // 0..127
                int c4  = (v & 3) << 2;       // 0,4,8,12
                float4 a = *reinterpret_cast<const float4*>(
                    &Ap[(size_t)(bm + row) * Kp + k0 + c4]);
                As[c4 + 0][row] = a.x;
                As[c4 + 1][row] = a.y;
                As[c4 + 2][row] = a.z;
                As[c4 + 3][row] = a.w;
            }
            // ---- load B tile (BK x BN) ----
#pragma unroll
            for (int vv = 0; vv < 2; ++vv) {
                int v   = tid + vv * 256;     // 0..511
                int row = v >> 5;             // 0..15
                int c4  = (v & 31) << 2;      // 0..124
                float4 b = *reinterpret_cast<const float4*>(
                    &Bp[(size_t)(k0 + row) * N + bn + c4]);
                *reinterpret_cast<float4*>(&Bs[row][c4]) = b;
            }
            __syncthreads();
            // ---- inner product ----
#pragma unroll
            for (int kk = 0; kk < BK; ++kk) {
                float ra[8], rb[8];
#pragma unroll
                for (int i = 0; i < 8; ++i) ra[i] = As[kk][ty + 16 * i];
#pragma unroll
                for (int j = 0; j < 8; ++j) rb[j] = Bs[kk][tx + 16 * j];
#pragma unroll
                for (int i = 0; i < 8; ++i)
#pragma unroll
                    for (int j = 0; j < 8; ++j)
                        acc[i][j] = fmaf(ra[i], rb[j], acc[i][j]);
            }
        }
    }

    // ---- epilogue ----
#pragma unroll
    for (int i = 0; i < 8; ++i) {
        int row = bm + ty + 16 * i;
        float scale = rscale ? rscale[row] : 1.0f;
#pragma unroll
        for (int j = 0; j < 8; ++j) {
            int col = bn + tx + 16 * j;
            float v = acc[i][j] * scale;
            if (bias) v += bias[col];
            if (doRelu) v = fmaxf(v, 0.0f);
            C[(size_t)row * N + col] = v;
        }
    }
}

// ---------------------------------------------------------------------------
// scores[n] = x2[n,:] . Wa + ba ; rowsum[n] = sum_f x2[n,f]
// ---------------------------------------------------------------------------
__global__ __launch_bounds__(256) void scores_rowsum_kernel(
    const float* __restrict__ x2, const float* __restrict__ Wa,
    const float* __restrict__ ba, float* __restrict__ scores,
    float* __restrict__ rowsum)
{
    int n = blockIdx.x;
    const float* row = x2 + (size_t)n * HID;
    float s = 0.0f, r = 0.0f;
    for (int f = threadIdx.x; f < HID; f += 256) {
        float v = row[f];
        s = fmaf(v, Wa[f], s);
        r += v;
    }
#pragma unroll
    for (int off = 32; off; off >>= 1) {
        s += __shfl_down(s, off);
        r += __shfl_down(r, off);
    }
    __shared__ float sred[4], rred[4];
    int tid = threadIdx.x;
    if ((tid & 63) == 0) { sred[tid >> 6] = s; rred[tid >> 6] = r; }
    __syncthreads();
    if (tid == 0) {
        scores[n] = sred[0] + sred[1] + sred[2] + sred[3] + ba[0];
        rowsum[n] = rred[0] + rred[1] + rred[2] + rred[3];
    }
}

// ---------------------------------------------------------------------------
// softmax over scores (axis=0, 2048 values) then ge[n] = w[n] * rowsum[n]
// ---------------------------------------------------------------------------
__global__ __launch_bounds__(256) void softmax_ge_kernel(
    const float* __restrict__ scores, const float* __restrict__ rowsum,
    float* __restrict__ ge)
{
    __shared__ float red[4];
    __shared__ float Msh, Zsh;
    int tid = threadIdx.x;

    float m = -1e30f;
    for (int n = tid; n < N_NODES; n += 256) m = fmaxf(m, scores[n]);
#pragma unroll
    for (int off = 32; off; off >>= 1) m = fmaxf(m, __shfl_down(m, off));
    if ((tid & 63) == 0) red[tid >> 6] = m;
    __syncthreads();
    if (tid == 0) Msh = fmaxf(fmaxf(red[0], red[1]), fmaxf(red[2], red[3]));
    __syncthreads();
    float M = Msh;

    float z = 0.0f;
    for (int n = tid; n < N_NODES; n += 256) z += expf(scores[n] - M);
#pragma unroll
    for (int off = 32; off; off >>= 1) z += __shfl_down(z, off);
    __syncthreads();
    if ((tid & 63) == 0) red[tid >> 6] = z;
    __syncthreads();
    if (tid == 0) Zsh = red[0] + red[1] + red[2] + red[3];
    __syncthreads();
    float Z = Zsh;

    for (int n = tid; n < N_NODES; n += 256)
        ge[n] = expf(scores[n] - M) / Z * rowsum[n];
}

// ---------------------------------------------------------------------------
// pooled[f] = mean_n x2[n,f] — two-stage column sum (no atomics, deterministic)
// ---------------------------------------------------------------------------
__global__ void pooled_part_kernel(const float* __restrict__ x2, float* __restrict__ partial) {
    int f  = blockIdx.x * 256 + threadIdx.x;   // 0..2047
    int r0 = blockIdx.y * 64;                  // 32 row chunks
    float s = 0.0f;
#pragma unroll 4
    for (int r = 0; r < 64; ++r) s += x2[(size_t)(r0 + r) * HID + f];
    partial[(size_t)blockIdx.y * HID + f] = s;
}

__global__ void pooled_final_kernel(const float* __restrict__ partial, float* __restrict__ pooled) {
    int f = blockIdx.x * 256 + threadIdx.x;
    float s = 0.0f;
#pragma unroll
    for (int r = 0; r < 32; ++r) s += partial[(size_t)r * HID + f];
    pooled[f] = s * (1.0f / N_NODES);
}

// ---------------------------------------------------------------------------
// out[c] = bf[c] + sum_j pooled[j]*Wf[j,c] + sum_j ge[j]*Wf[HID+j,c]
// ---------------------------------------------------------------------------
__global__ __launch_bounds__(256) void final_kernel(
    const float* __restrict__ pooled, const float* __restrict__ ge,
    const float* __restrict__ Wf, const float* __restrict__ bf,
    float* __restrict__ out)
{
    __shared__ float part[16][NCLS];
    int tid = threadIdx.x;
    int c = tid & 15, g = tid >> 4;
    float s = 0.0f;
    for (int j = g; j < HID; j += 16) {
        s = fmaf(pooled[j], Wf[(size_t)j * NCLS + c], s);
        s = fmaf(ge[j],     Wf[(size_t)(HID + j) * NCLS + c], s);
    }
    part[g][c] = s;
    __syncthreads();
    if (g == 0) {
        float t = 0.0f;
#pragma unroll
        for (int gg = 0; gg < 16; ++gg) t += part[gg][c];
        out[c] = t + bf[c];
    }
}

// ---------------------------------------------------------------------------
extern "C" void kernel_launch(void* const* d_in, const int* in_sizes, int n_in,
                              void* d_out, int out_size, void* d_ws, size_t ws_size,
                              hipStream_t stream) {
    const float* x   = (const float*)d_in[0];
    const int*   src = (const int*)  d_in[1];
    const int*   dst = (const int*)  d_in[2];
    const float* W1l = (const float*)d_in[3];
    const float* b1  = (const float*)d_in[4];
    const float* W1r = (const float*)d_in[5];
    const float* W2l = (const float*)d_in[6];
    const float* b2  = (const float*)d_in[7];
    const float* W2r = (const float*)d_in[8];
    const float* Wa  = (const float*)d_in[9];
    const float* ba  = (const float*)d_in[10];
    const float* Wf  = (const float*)d_in[11];
    const float* bf  = (const float*)d_in[12];
    float* out = (float*)d_out;

    float* ws     = (float*)d_ws;
    float* adj    = ws;                                  // 2048*2048
    float* mean   = adj  + (size_t)N_NODES * N_NODES;    // 2048*2048 (mean1 uses 2048*512)
    float* x1     = mean + (size_t)N_NODES * HID;        // 2048*2048
    float* x2     = x1   + (size_t)N_NODES * HID;        // 2048*2048
    float* cnt    = x2   + (size_t)N_NODES * HID;        // 2048
    float* rsc    = cnt    + N_NODES;                    // 2048
    float* scores = rsc    + N_NODES;                    // 2048
    float* rowsum = scores + N_NODES;                    // 2048
    float* ge     = rowsum + N_NODES;                    // 2048
    float* pooled = ge     + N_NODES;                    // 2048
    float* partial= pooled + HID;                        // 32*2048

    hipMemsetAsync(adj, 0, (size_t)N_NODES * N_NODES * sizeof(float), stream);
    hipMemsetAsync(cnt, 0, (size_t)N_NODES * sizeof(float), stream);

    build_adj_kernel<<<E_EDGES / 256, 256, 0, stream>>>(src, dst, adj, cnt);
    rscale_kernel<<<N_NODES / 256, 256, 0, stream>>>(cnt, rsc);

    // mean1 = rowscale(adj @ x)                [2048, 512]
    gemm_f32<<<dim3(IN_DIM / BN, N_NODES / BM), 256, 0, stream>>>(
        adj, x, N_NODES, nullptr, nullptr, 0, nullptr, rsc, mean, N_NODES, IN_DIM, 0);
    // x1 = relu(mean1 @ W1l + x @ W1r + b1)    [2048, 2048]
    gemm_f32<<<dim3(HID / BN, N_NODES / BM), 256, 0, stream>>>(
        mean, W1l, IN_DIM, x, W1r, IN_DIM, b1, nullptr, x1, N_NODES, HID, 1);
    // mean2 = rowscale(adj @ x1)               [2048, 2048]
    gemm_f32<<<dim3(HID / BN, N_NODES / BM), 256, 0, stream>>>(
        adj, x1, N_NODES, nullptr, nullptr, 0, nullptr, rsc, mean, N_NODES, HID, 0);
    // x2 = relu(mean2 @ W2l + x1 @ W2r + b2)   [2048, 2048]
    gemm_f32<<<dim3(HID / BN, N_NODES / BM), 256, 0, stream>>>(
        mean, W2l, HID, x1, W2r, HID, b2, nullptr, x2, N_NODES, HID, 1);

    scores_rowsum_kernel<<<N_NODES, 256, 0, stream>>>(x2, Wa, ba, scores, rowsum);
    softmax_ge_kernel<<<1, 256, 0, stream>>>(scores, rowsum, ge);
    pooled_part_kernel<<<dim3(HID / 256, 32), 256, 0, stream>>>(x2, partial);
    pooled_final_kernel<<<HID / 256, 256, 0, stream>>>(partial, pooled);
    final_kernel<<<1, 256, 0, stream>>>(pooled, ge, Wf, bf, out);
}

// Round 2
// 394.767 us; speedup vs baseline: 3.7652x; 3.7652x over previous
//
#include <hip/hip_runtime.h>
#include <hip/hip_bf16.h>
#include <cstddef>
#include <cstdint>

#define N_NODES 2048
#define E_EDGES 131072
#define IN_DIM  512
#define HID     2048
#define NCLS    16

typedef __bf16 bf16x8 __attribute__((ext_vector_type(8)));
typedef short  s16x4  __attribute__((ext_vector_type(4)));
typedef short  s16x8  __attribute__((ext_vector_type(8)));
typedef float  f32x4  __attribute__((ext_vector_type(4)));

__device__ __forceinline__ unsigned short f2bf(float f) {
  unsigned u = __builtin_bit_cast(unsigned, f);
  u = (u + 0x7FFFu + ((u >> 16) & 1u)) >> 16;
  return (unsigned short)u;
}

#define GLD16(gp, lp) __builtin_amdgcn_global_load_lds(                     \
    (__attribute__((address_space(1))) void*)(gp),                          \
    (__attribute__((address_space(3))) void*)(lp), 16, 0, 0)

// ---------------------------------------------------------------------------
// Dense adjacency build (fp32 atomics; counts are exact small ints)
// ---------------------------------------------------------------------------
__global__ void build_adj_kernel(const int* __restrict__ src, const int* __restrict__ dst,
                                 float* __restrict__ adj, float* __restrict__ cnt) {
  int e = blockIdx.x * blockDim.x + threadIdx.x;
  if (e < E_EDGES) {
    int s = src[e], d = dst[e];
    atomicAdd(&adj[(size_t)d * N_NODES + s], 1.0f);
    atomicAdd(&cnt[d], 1.0f);
  }
}

__global__ void rscale_kernel(const float* __restrict__ cnt, float* __restrict__ rscale) {
  int i = blockIdx.x * blockDim.x + threadIdx.x;
  if (i < N_NODES) rscale[i] = 1.0f / fmaxf(cnt[i], 1.0f);
}

// ---------------------------------------------------------------------------
// fp32 -> bf16 elementwise (same layout), vectorized x4
// ---------------------------------------------------------------------------
__global__ void cvt_f32_bf16(const float* __restrict__ in, short* __restrict__ out, int n4) {
  int i = blockIdx.x * blockDim.x + threadIdx.x;
  if (i < n4) {
    float4 v = reinterpret_cast<const float4*>(in)[i];
    s16x4 o;
    o[0] = (short)f2bf(v.x); o[1] = (short)f2bf(v.y);
    o[2] = (short)f2bf(v.z); o[3] = (short)f2bf(v.w);
    reinterpret_cast<s16x4*>(out)[i] = o;
  }
}

// ---------------------------------------------------------------------------
// Transposes: in [R][C] -> out [C][R]; 32x32 LDS tiles, conflict-free (+1 pad)
// ---------------------------------------------------------------------------
__global__ __launch_bounds__(256) void tr_f32_bf16(const float* __restrict__ in,
                                                   short* __restrict__ out, int R, int C) {
  __shared__ float t[32][33];
  int c0 = blockIdx.x * 32, r0 = blockIdx.y * 32;
  int tx = threadIdx.x & 31, ty = threadIdx.x >> 5;
#pragma unroll
  for (int i = 0; i < 4; ++i)
    t[ty + 8 * i][tx] = in[(size_t)(r0 + ty + 8 * i) * C + c0 + tx];
  __syncthreads();
#pragma unroll
  for (int i = 0; i < 4; ++i)
    out[(size_t)(c0 + ty + 8 * i) * R + r0 + tx] = (short)f2bf(t[tx][ty + 8 * i]);
}

__global__ __launch_bounds__(256) void tr_bf16(const short* __restrict__ in,
                                               short* __restrict__ out, int R, int C) {
  __shared__ short t[32][33];
  int c0 = blockIdx.x * 32, r0 = blockIdx.y * 32;
  int tx = threadIdx.x & 31, ty = threadIdx.x >> 5;
#pragma unroll
  for (int i = 0; i < 4; ++i)
    t[ty + 8 * i][tx] = in[(size_t)(r0 + ty + 8 * i) * C + c0 + tx];
  __syncthreads();
#pragma unroll
  for (int i = 0; i < 4; ++i)
    out[(size_t)(c0 + ty + 8 * i) * R + r0 + tx] = t[tx][ty + 8 * i];
}

// ---------------------------------------------------------------------------
// bf16 MFMA GEMM.  C[M,N] = A1@B1 (+ A2@B2) with B given TRANSPOSED [N][K].
// BM=64, BN=128, BK=32; 256 threads = 4 waves; wave w owns cols w*32..w*32+31.
// LDS tiles stored row-major [row][32k] with 16B units XOR-swizzled by row&3
// (pre-swizzled global source; global_load_lds writes linearly). Fragment
// reads are per-lane ds_read_b64 pairs at the swizzled offsets -> uniform
// 4-way/bank-pair = b64 floor. fp32 accumulate; epilogue: rscale[row],
// bias[col], relu; writes fp32 Cf and/or bf16 Cb.
// mfma_f32_16x16x32_bf16 layout: A lane: row=l&15, k=(l>>4)*4+(j&3)+16*(j>>2);
// B lane: col=l&15, same k map; D: col=l&15, row=(l>>4)*4+reg  [m89/m162].
// ---------------------------------------------------------------------------
__global__ __launch_bounds__(256) void gemm_bf16(
    const short* __restrict__ A1, const short* __restrict__ B1t, int K1,
    const short* __restrict__ A2, const short* __restrict__ B2t, int K2,
    const float* __restrict__ bias, const float* __restrict__ rscale,
    float* __restrict__ Cf, short* __restrict__ Cb, int N, int doRelu)
{
  __shared__ short As[64 * 32];    // 4 KB
  __shared__ short Bs[128 * 32];   // 8 KB

  const int tid  = threadIdx.x;
  const int wid  = tid >> 6;
  const int lane = tid & 63;
  const int g    = lane >> 4;
  const int r16  = lane & 15;
  const int bm   = blockIdx.y * 64;
  const int bn   = blockIdx.x * 128;

  f32x4 acc[4][2];
#pragma unroll
  for (int mi = 0; mi < 4; ++mi)
#pragma unroll
    for (int ni = 0; ni < 2; ++ni)
#pragma unroll
      for (int r = 0; r < 4; ++r) acc[mi][ni][r] = 0.0f;

#pragma unroll 1
  for (int pass = 0; pass < 2; ++pass) {
    const short* Ap = pass ? A2 : A1;
    const short* Bp = pass ? B2t : B1t;
    const int    Kp = pass ? K2 : K1;
    if (Kp == 0) continue;

#pragma unroll 1
    for (int k0 = 0; k0 < Kp; k0 += 32) {
      __syncthreads();   // all waves done reading previous tiles
      {  // stage A: 256 16B-units, 1 inst/wave
        int U = wid * 64 + lane;
        int m = U >> 2;
        int u = (U & 3) ^ (m & 3);
        const short* gp = Ap + (size_t)(bm + m) * Kp + k0 + u * 8;
        GLD16(gp, &As[wid * 512]);
      }
#pragma unroll
      for (int i = 0; i < 2; ++i) {  // stage B: 512 units, 2 inst/wave
        int U = wid * 128 + i * 64 + lane;
        int n = U >> 2;
        int u = (U & 3) ^ (n & 3);
        const short* gp = Bp + (size_t)(bn + n) * Kp + k0 + u * 8;
        GLD16(gp, &Bs[(wid * 128 + i * 64) * 8]);
      }
      __syncthreads();   // drains vmcnt(0): tiles resident

      bf16x8 a[4], b[2];
#pragma unroll
      for (int mi = 0; mi < 4; ++mi) {
        int m = mi * 16 + r16;
        int s = m & 3;
        s16x4 lo = *(const s16x4*)&As[m * 32 + ((((g >> 1)    ) ^ s) << 3) + ((g & 1) << 2)];
        s16x4 hi = *(const s16x4*)&As[m * 32 + (((2 | (g >> 1)) ^ s) << 3) + ((g & 1) << 2)];
        a[mi] = __builtin_bit_cast(bf16x8, __builtin_shufflevector(lo, hi, 0, 1, 2, 3, 4, 5, 6, 7));
      }
#pragma unroll
      for (int ni = 0; ni < 2; ++ni) {
        int n = wid * 32 + ni * 16 + r16;
        int s = n & 3;
        s16x4 lo = *(const s16x4*)&Bs[n * 32 + ((((g >> 1)    ) ^ s) << 3) + ((g & 1) << 2)];
        s16x4 hi = *(const s16x4*)&Bs[n * 32 + (((2 | (g >> 1)) ^ s) << 3) + ((g & 1) << 2)];
        b[ni] = __builtin_bit_cast(bf16x8, __builtin_shufflevector(lo, hi, 0, 1, 2, 3, 4, 5, 6, 7));
      }
#pragma unroll
      for (int mi = 0; mi < 4; ++mi)
#pragma unroll
        for (int ni = 0; ni < 2; ++ni)
          acc[mi][ni] = __builtin_amdgcn_mfma_f32_16x16x32_bf16(a[mi], b[ni], acc[mi][ni], 0, 0, 0);
    }
  }

  // epilogue
#pragma unroll
  for (int mi = 0; mi < 4; ++mi) {
#pragma unroll
    for (int r = 0; r < 4; ++r) {
      int row = bm + mi * 16 + (lane >> 4) * 4 + r;
      float scale = rscale ? rscale[row] : 1.0f;
#pragma unroll
      for (int ni = 0; ni < 2; ++ni) {
        int col = bn + wid * 32 + ni * 16 + r16;
        float v = acc[mi][ni][r] * scale;
        if (bias)  v += bias[col];
        if (doRelu) v = fmaxf(v, 0.0f);
        if (Cf) Cf[(size_t)row * N + col] = v;
        if (Cb) Cb[(size_t)row * N + col] = (short)f2bf(v);
      }
    }
  }
}

// ---------------------------------------------------------------------------
// Head (unchanged, fp32): scores/rowsum, softmax+ge, pooled, final linear
// ---------------------------------------------------------------------------
__global__ __launch_bounds__(256) void scores_rowsum_kernel(
    const float* __restrict__ x2, const float* __restrict__ Wa,
    const float* __restrict__ ba, float* __restrict__ scores,
    float* __restrict__ rowsum)
{
  int n = blockIdx.x;
  const float* row = x2 + (size_t)n * HID;
  float s = 0.0f, r = 0.0f;
  for (int f = threadIdx.x; f < HID; f += 256) {
    float v = row[f];
    s = fmaf(v, Wa[f], s);
    r += v;
  }
#pragma unroll
  for (int off = 32; off; off >>= 1) {
    s += __shfl_down(s, off);
    r += __shfl_down(r, off);
  }
  __shared__ float sred[4], rred[4];
  int tid = threadIdx.x;
  if ((tid & 63) == 0) { sred[tid >> 6] = s; rred[tid >> 6] = r; }
  __syncthreads();
  if (tid == 0) {
    scores[n] = sred[0] + sred[1] + sred[2] + sred[3] + ba[0];
    rowsum[n] = rred[0] + rred[1] + rred[2] + rred[3];
  }
}

__global__ __launch_bounds__(256) void softmax_ge_kernel(
    const float* __restrict__ scores, const float* __restrict__ rowsum,
    float* __restrict__ ge)
{
  __shared__ float red[4];
  __shared__ float Msh, Zsh;
  int tid = threadIdx.x;

  float m = -1e30f;
  for (int n = tid; n < N_NODES; n += 256) m = fmaxf(m, scores[n]);
#pragma unroll
  for (int off = 32; off; off >>= 1) m = fmaxf(m, __shfl_down(m, off));
  if ((tid & 63) == 0) red[tid >> 6] = m;
  __syncthreads();
  if (tid == 0) Msh = fmaxf(fmaxf(red[0], red[1]), fmaxf(red[2], red[3]));
  __syncthreads();
  float M = Msh;

  float z = 0.0f;
  for (int n = tid; n < N_NODES; n += 256) z += expf(scores[n] - M);
#pragma unroll
  for (int off = 32; off; off >>= 1) z += __shfl_down(z, off);
  __syncthreads();
  if ((tid & 63) == 0) red[tid >> 6] = z;
  __syncthreads();
  if (tid == 0) Zsh = red[0] + red[1] + red[2] + red[3];
  __syncthreads();
  float Z = Zsh;

  for (int n = tid; n < N_NODES; n += 256)
    ge[n] = expf(scores[n] - M) / Z * rowsum[n];
}

__global__ void pooled_part_kernel(const float* __restrict__ x2, float* __restrict__ partial) {
  int f  = blockIdx.x * 256 + threadIdx.x;
  int r0 = blockIdx.y * 64;
  float s = 0.0f;
#pragma unroll 4
  for (int r = 0; r < 64; ++r) s += x2[(size_t)(r0 + r) * HID + f];
  partial[(size_t)blockIdx.y * HID + f] = s;
}

__global__ void pooled_final_kernel(const float* __restrict__ partial, float* __restrict__ pooled) {
  int f = blockIdx.x * 256 + threadIdx.x;
  float s = 0.0f;
#pragma unroll
  for (int r = 0; r < 32; ++r) s += partial[(size_t)r * HID + f];
  pooled[f] = s * (1.0f / N_NODES);
}

__global__ __launch_bounds__(256) void final_kernel(
    const float* __restrict__ pooled, const float* __restrict__ ge,
    const float* __restrict__ Wf, const float* __restrict__ bf,
    float* __restrict__ out)
{
  __shared__ float part[16][NCLS];
  int tid = threadIdx.x;
  int c = tid & 15, gg = tid >> 4;
  float s = 0.0f;
  for (int j = gg; j < HID; j += 16) {
    s = fmaf(pooled[j], Wf[(size_t)j * NCLS + c], s);
    s = fmaf(ge[j],     Wf[(size_t)(HID + j) * NCLS + c], s);
  }
  part[gg][c] = s;
  __syncthreads();
  if (gg == 0) {
    float t = 0.0f;
#pragma unroll
    for (int k = 0; k < 16; ++k) t += part[k][c];
    out[c] = t + bf[c];
  }
}

// ---------------------------------------------------------------------------
extern "C" void kernel_launch(void* const* d_in, const int* in_sizes, int n_in,
                              void* d_out, int out_size, void* d_ws, size_t ws_size,
                              hipStream_t stream) {
  const float* x   = (const float*)d_in[0];
  const int*   src = (const int*)  d_in[1];
  const int*   dst = (const int*)  d_in[2];
  const float* W1l = (const float*)d_in[3];
  const float* b1  = (const float*)d_in[4];
  const float* W1r = (const float*)d_in[5];
  const float* W2l = (const float*)d_in[6];
  const float* b2  = (const float*)d_in[7];
  const float* W2r = (const float*)d_in[8];
  const float* Wa  = (const float*)d_in[9];
  const float* ba  = (const float*)d_in[10];
  const float* Wf  = (const float*)d_in[11];
  const float* bf  = (const float*)d_in[12];
  float* out = (float*)d_out;

  const size_t MB = 1u << 20;
  char* w = (char*)d_ws;
  float* adj   = (float*)(w);              // 16MB, dead after cvt -> reused as x2
  float* x2    = (float*)(w);              // 16MB (gemm4 output)
  short* adjb  = (short*)(w + 16 * MB);    // 8MB
  short* xb    = (short*)(w + 24 * MB);    // 2MB   (dead after gemm2)
  short* xT    = (short*)(w + 26 * MB);    // 2MB   (dead after gemm1)
  short* W1lT  = (short*)(w + 28 * MB);    // 2MB   (dead after gemm2)
  short* W1rT  = (short*)(w + 30 * MB);    // 2MB   (dead after gemm2)
  short* x1T   = (short*)(w + 24 * MB);    // 8MB, overlays xb/xT/W1lT/W1rT
  short* W2lT  = (short*)(w + 32 * MB);    // 8MB
  short* W2rT  = (short*)(w + 40 * MB);    // 8MB
  short* meanb = (short*)(w + 48 * MB);    // 8MB (mean1b then mean2b)
  short* x1b   = (short*)(w + 56 * MB);    // 8MB
  float* cnt    = (float*)(w + 64 * MB);
  float* rsc    = cnt    + N_NODES;
  float* scores = rsc    + N_NODES;
  float* rowsum = scores + N_NODES;
  float* ge     = rowsum + N_NODES;
  float* pooled = ge     + N_NODES;
  float* partial= pooled + HID;            // 32*2048

  hipMemsetAsync(adj, 0, (size_t)N_NODES * N_NODES * sizeof(float), stream);
  hipMemsetAsync(cnt, 0, (size_t)N_NODES * sizeof(float), stream);

  build_adj_kernel<<<E_EDGES / 256, 256, 0, stream>>>(src, dst, adj, cnt);
  rscale_kernel<<<N_NODES / 256, 256, 0, stream>>>(cnt, rsc);

  // conversions / transposes to bf16
  cvt_f32_bf16<<<(N_NODES * N_NODES / 4 + 255) / 256, 256, 0, stream>>>(adj, adjb, N_NODES * N_NODES / 4);
  cvt_f32_bf16<<<(N_NODES * IN_DIM / 4 + 255) / 256, 256, 0, stream>>>(x, xb, N_NODES * IN_DIM / 4);
  tr_f32_bf16<<<dim3(IN_DIM / 32, N_NODES / 32), 256, 0, stream>>>(x,   xT,   N_NODES, IN_DIM);
  tr_f32_bf16<<<dim3(HID / 32, IN_DIM / 32),     256, 0, stream>>>(W1l, W1lT, IN_DIM,  HID);
  tr_f32_bf16<<<dim3(HID / 32, IN_DIM / 32),     256, 0, stream>>>(W1r, W1rT, IN_DIM,  HID);
  tr_f32_bf16<<<dim3(HID / 32, HID / 32),        256, 0, stream>>>(W2l, W2lT, HID,     HID);
  tr_f32_bf16<<<dim3(HID / 32, HID / 32),        256, 0, stream>>>(W2r, W2rT, HID,     HID);

  // mean1 = rowscale(adj @ x)        [2048, 512] bf16
  gemm_bf16<<<dim3(IN_DIM / 128, N_NODES / 64), 256, 0, stream>>>(
      adjb, xT, N_NODES, nullptr, nullptr, 0, nullptr, rsc, nullptr, meanb, IN_DIM, 0);
  // x1 = relu(mean1 @ W1l + x @ W1r + b1)   [2048, 2048] bf16
  gemm_bf16<<<dim3(HID / 128, N_NODES / 64), 256, 0, stream>>>(
      meanb, W1lT, IN_DIM, xb, W1rT, IN_DIM, b1, nullptr, nullptr, x1b, HID, 1);
  // x1T
  tr_bf16<<<dim3(HID / 32, N_NODES / 32), 256, 0, stream>>>(x1b, x1T, N_NODES, HID);
  // mean2 = rowscale(adj @ x1)       [2048, 2048] bf16
  gemm_bf16<<<dim3(HID / 128, N_NODES / 64), 256, 0, stream>>>(
      adjb, x1T, N_NODES, nullptr, nullptr, 0, nullptr, rsc, nullptr, meanb, HID, 0);
  // x2 = relu(mean2 @ W2l + x1 @ W2r + b2)  [2048, 2048] fp32
  gemm_bf16<<<dim3(HID / 128, N_NODES / 64), 256, 0, stream>>>(
      meanb, W2lT, HID, x1b, W2rT, HID, b2, nullptr, x2, nullptr, HID, 1);

  scores_rowsum_kernel<<<N_NODES, 256, 0, stream>>>(x2, Wa, ba, scores, rowsum);
  softmax_ge_kernel<<<1, 256, 0, stream>>>(scores, rowsum, ge);
  pooled_part_kernel<<<dim3(HID / 256, 32), 256, 0, stream>>>(x2, partial);
  pooled_final_kernel<<<HID / 256, 256, 0, stream>>>(partial, pooled);
  final_kernel<<<1, 256, 0, stream>>>(pooled, ge, Wf, bf, out);
}

// Round 3
// 296.868 us; speedup vs baseline: 5.0069x; 1.3298x over previous
//
#include <hip/hip_runtime.h>
#include <hip/hip_bf16.h>
#include <cstddef>
#include <cstdint>

#define N_NODES 2048
#define E_EDGES 131072
#define IN_DIM  512
#define HID     2048
#define NCLS    16

typedef __bf16 bf16x8 __attribute__((ext_vector_type(8)));
typedef short  s16x4  __attribute__((ext_vector_type(4)));
typedef short  s16x8  __attribute__((ext_vector_type(8)));
typedef float  f32x4  __attribute__((ext_vector_type(4)));

__device__ __forceinline__ unsigned short f2bf(float f) {
  unsigned u = __builtin_bit_cast(unsigned, f);
  u = (u + 0x7FFFu + ((u >> 16) & 1u)) >> 16;
  return (unsigned short)u;
}

// K-permutation within each 32-col block: logical k stored at slot pos32(k).
// Lane g's 8-elem fragment (k = g*4+{0..3}, g*4+16+{0..3}) = contiguous slots
// [8g, 8g+8) = one 16B unit -> single ds_read_b128 per fragment.
// pos32 is a 3-cycle on bits (4->2->3->4); inverse = pos32 applied twice.
__device__ __forceinline__ int pos32(int k) {
  return (((k >> 2) & 3) << 3) | (((k >> 4) & 1) << 2) | (k & 3);
}

#define GLD16(gp, lp) __builtin_amdgcn_global_load_lds(                     \
    (__attribute__((address_space(1))) void*)(gp),                          \
    (__attribute__((address_space(3))) void*)(lp), 16, 0, 0)

// ---------------------------------------------------------------------------
// Dense adjacency build; columns stored K-PERMUTED (fold perm into atomics).
// ---------------------------------------------------------------------------
__global__ void build_adj_kernel(const int* __restrict__ src, const int* __restrict__ dst,
                                 float* __restrict__ adj, float* __restrict__ cnt) {
  int e = blockIdx.x * blockDim.x + threadIdx.x;
  if (e < E_EDGES) {
    int s = src[e], d = dst[e];
    int sp = (s & ~31) | pos32(s & 31);
    atomicAdd(&adj[(size_t)d * N_NODES + sp], 1.0f);
    atomicAdd(&cnt[d], 1.0f);
  }
}

__global__ void rscale_kernel(const float* __restrict__ cnt, float* __restrict__ rscale) {
  int i = blockIdx.x * blockDim.x + threadIdx.x;
  if (i < N_NODES) rscale[i] = 1.0f / fmaxf(cnt[i], 1.0f);
}

// plain fp32->bf16 (layout preserved; used for adj which is already permuted)
__global__ void cvt_f32_bf16(const float* __restrict__ in, short* __restrict__ out, int n4) {
  int i = blockIdx.x * blockDim.x + threadIdx.x;
  if (i < n4) {
    float4 v = reinterpret_cast<const float4*>(in)[i];
    s16x4 o;
    o[0] = (short)f2bf(v.x); o[1] = (short)f2bf(v.y);
    o[2] = (short)f2bf(v.z); o[3] = (short)f2bf(v.w);
    reinterpret_cast<s16x4*>(out)[i] = o;
  }
}

// fp32->bf16 with K-permuted column slots (row length % 32 == 0)
__global__ void cvt_perm_f32_bf16(const float* __restrict__ in, short* __restrict__ out, int n4) {
  int i = blockIdx.x * blockDim.x + threadIdx.x;
  if (i < n4) {
    size_t flat = (size_t)i * 4;
    float4 v = *reinterpret_cast<const float4*>(&in[flat]);
    s16x4 o;
    o[0] = (short)f2bf(v.x); o[1] = (short)f2bf(v.y);
    o[2] = (short)f2bf(v.z); o[3] = (short)f2bf(v.w);
    size_t base = (flat & ~(size_t)31) | (size_t)pos32((int)(flat & 31));
    *reinterpret_cast<s16x4*>(&out[base]) = o;
  }
}

// ---------------------------------------------------------------------------
// Transpose fp32 [R][C] -> bf16 [C][R] with K-permuted slots over R (=k dim).
// out[(c)*R + r0 + p] holds logical k = r0 + invpos(p).
// ---------------------------------------------------------------------------
__global__ __launch_bounds__(256) void tr_f32_bf16_perm(const float* __restrict__ in,
                                                        short* __restrict__ out, int R, int C) {
  __shared__ float t[32][33];
  int c0 = blockIdx.x * 32, r0 = blockIdx.y * 32;
  int tx = threadIdx.x & 31, ty = threadIdx.x >> 5;
#pragma unroll
  for (int i = 0; i < 4; ++i)
    t[ty + 8 * i][tx] = in[(size_t)(r0 + ty + 8 * i) * C + c0 + tx];
  __syncthreads();
  int ip = pos32(pos32(tx));   // invpos
#pragma unroll
  for (int i = 0; i < 4; ++i)
    out[(size_t)(c0 + ty + 8 * i) * R + r0 + tx] = (short)f2bf(t[ip][ty + 8 * i]);
}

// ---------------------------------------------------------------------------
// Transpose bf16-permuted [R][C] -> bf16-permuted [C][R] (both sides slotted).
// in[r][p] = logical (r, c0+invpos(p)); out[c][q] = logical (invpos(q), c).
// ---------------------------------------------------------------------------
__global__ __launch_bounds__(256) void tr_bf16_perm2(const short* __restrict__ in,
                                                     short* __restrict__ out, int R, int C) {
  __shared__ short t[32][33];
  int c0 = blockIdx.x * 32, r0 = blockIdx.y * 32;
  int tx = threadIdx.x & 31, ty = threadIdx.x >> 5;
#pragma unroll
  for (int i = 0; i < 4; ++i)
    t[ty + 8 * i][tx] = in[(size_t)(r0 + ty + 8 * i) * C + c0 + tx];
  __syncthreads();
  int iq = pos32(pos32(tx));   // invpos
#pragma unroll
  for (int i = 0; i < 4; ++i) {
    int cl = ty + 8 * i;
    out[(size_t)(c0 + cl) * R + r0 + tx] = t[iq][pos32(cl)];
  }
}

// ---------------------------------------------------------------------------
// bf16 MFMA GEMM, z-packed K/operand slices -> fp32 partials P[z][M][N].
// Block tile 128x128, 4 waves (2x2), wave tile 64x64, BK=32.
// Operands are [rows][K] bf16 with K-permuted slots; LDS rows of 32 shorts,
// 16B units XOR-swizzled by (row&3) via pre-swizzled global src; fragment =
// one ds_read_b128 at unit g^(row&3) -> uniform 8/bank (floor).
// z < n1: pair1 K-slice z of n1; z >= n1: whole pair2 (K2).
// ---------------------------------------------------------------------------
__global__ __launch_bounds__(256) void gemm_z(
    const short* __restrict__ A1, const short* __restrict__ B1, int K1, int n1,
    const short* __restrict__ A2, const short* __restrict__ B2, int K2,
    float* __restrict__ P, int M, int N)
{
  __shared__ short As[128 * 32];   // 8 KB
  __shared__ short Bs[128 * 32];   // 8 KB

  const int z = blockIdx.z;
  const short* A; const short* B; int lda, k0, kend;
  if (z < n1) { A = A1; B = B1; lda = K1; int ks = K1 / n1; k0 = z * ks; kend = k0 + ks; }
  else        { A = A2; B = B2; lda = K2; k0 = 0; kend = K2; }
  float* Pz = P + (size_t)z * M * N;

  const int tid = threadIdx.x, wid = tid >> 6, lane = tid & 63;
  const int g = lane >> 4, r16 = lane & 15;
  const int wm = (wid >> 1) * 64, wn = (wid & 1) * 64;
  const int bm = blockIdx.y * 128, bn = blockIdx.x * 128;

  f32x4 acc[4][4];
#pragma unroll
  for (int mi = 0; mi < 4; ++mi)
#pragma unroll
    for (int ni = 0; ni < 4; ++ni)
#pragma unroll
      for (int r = 0; r < 4; ++r) acc[mi][ni][r] = 0.0f;

#pragma unroll 1
  for (int k = k0; k < kend; k += 32) {
    __syncthreads();   // previous tiles fully consumed
#pragma unroll
    for (int h = 0; h < 2; ++h) {   // stage A: 512 16B-units
      int U = h * 256 + wid * 64 + lane;
      int m = U >> 2, u = (U & 3) ^ (m & 3);
      GLD16(A + (size_t)(bm + m) * lda + k + u * 8, &As[(h * 256 + wid * 64) * 8]);
    }
#pragma unroll
    for (int h = 0; h < 2; ++h) {   // stage B: 512 16B-units
      int U = h * 256 + wid * 64 + lane;
      int n = U >> 2, u = (U & 3) ^ (n & 3);
      GLD16(B + (size_t)(bn + n) * lda + k + u * 8, &Bs[(h * 256 + wid * 64) * 8]);
    }
    __syncthreads();   // vmcnt(0): tiles resident

    bf16x8 a[4], b[4];
#pragma unroll
    for (int mi = 0; mi < 4; ++mi) {
      int m = wm + mi * 16 + r16;
      a[mi] = __builtin_bit_cast(bf16x8, *(const s16x8*)&As[m * 32 + ((g ^ (m & 3)) << 3)]);
    }
#pragma unroll
    for (int ni = 0; ni < 4; ++ni) {
      int n = wn + ni * 16 + r16;
      b[ni] = __builtin_bit_cast(bf16x8, *(const s16x8*)&Bs[n * 32 + ((g ^ (n & 3)) << 3)]);
    }
#pragma unroll
    for (int mi = 0; mi < 4; ++mi)
#pragma unroll
      for (int ni = 0; ni < 4; ++ni)
        acc[mi][ni] = __builtin_amdgcn_mfma_f32_16x16x32_bf16(a[mi], b[ni], acc[mi][ni], 0, 0, 0);
  }

#pragma unroll
  for (int mi = 0; mi < 4; ++mi)
#pragma unroll
    for (int r = 0; r < 4; ++r) {
      int row = bm + wm + mi * 16 + g * 4 + r;
#pragma unroll
      for (int ni = 0; ni < 4; ++ni) {
        int col = bn + wn + ni * 16 + r16;
        Pz[(size_t)row * N + col] = acc[mi][ni][r];
      }
    }
}

// ---------------------------------------------------------------------------
// Combine z-partials: sum, optional rscale[row]/bias[col]/relu; write fp32
// plain and/or bf16 K-permuted.
// ---------------------------------------------------------------------------
__global__ __launch_bounds__(256) void combine_kernel(
    const float* __restrict__ P, int nz, size_t MN,
    const float* __restrict__ rsc, int rshift,
    const float* __restrict__ bias, int cmask, int doRelu,
    short* __restrict__ outb, float* __restrict__ outf)
{
  size_t i4 = (size_t)blockIdx.x * 256 + threadIdx.x;
  size_t flat = i4 * 4;
  if (flat >= MN) return;
  float4 s = *reinterpret_cast<const float4*>(&P[flat]);
#pragma unroll 1
  for (int zz = 1; zz < nz; ++zz) {
    float4 t = *reinterpret_cast<const float4*>(&P[(size_t)zz * MN + flat]);
    s.x += t.x; s.y += t.y; s.z += t.z; s.w += t.w;
  }
  if (rsc) {
    float sc = rsc[flat >> rshift];
    s.x *= sc; s.y *= sc; s.z *= sc; s.w *= sc;
  }
  if (bias) {
    float4 bv = *reinterpret_cast<const float4*>(&bias[flat & (size_t)cmask]);
    s.x += bv.x; s.y += bv.y; s.z += bv.z; s.w += bv.w;
  }
  if (doRelu) {
    s.x = fmaxf(s.x, 0.0f); s.y = fmaxf(s.y, 0.0f);
    s.z = fmaxf(s.z, 0.0f); s.w = fmaxf(s.w, 0.0f);
  }
  if (outf) *reinterpret_cast<float4*>(&outf[flat]) = s;
  if (outb) {
    s16x4 o;
    o[0] = (short)f2bf(s.x); o[1] = (short)f2bf(s.y);
    o[2] = (short)f2bf(s.z); o[3] = (short)f2bf(s.w);
    size_t base = (flat & ~(size_t)31) | (size_t)pos32((int)(flat & 31));
    *reinterpret_cast<s16x4*>(&outb[base]) = o;
  }
}

// ---------------------------------------------------------------------------
// Head (fp32, unchanged)
// ---------------------------------------------------------------------------
__global__ __launch_bounds__(256) void scores_rowsum_kernel(
    const float* __restrict__ x2, const float* __restrict__ Wa,
    const float* __restrict__ ba, float* __restrict__ scores,
    float* __restrict__ rowsum)
{
  int n = blockIdx.x;
  const float* row = x2 + (size_t)n * HID;
  float s = 0.0f, r = 0.0f;
  for (int f = threadIdx.x; f < HID; f += 256) {
    float v = row[f];
    s = fmaf(v, Wa[f], s);
    r += v;
  }
#pragma unroll
  for (int off = 32; off; off >>= 1) {
    s += __shfl_down(s, off);
    r += __shfl_down(r, off);
  }
  __shared__ float sred[4], rred[4];
  int tid = threadIdx.x;
  if ((tid & 63) == 0) { sred[tid >> 6] = s; rred[tid >> 6] = r; }
  __syncthreads();
  if (tid == 0) {
    scores[n] = sred[0] + sred[1] + sred[2] + sred[3] + ba[0];
    rowsum[n] = rred[0] + rred[1] + rred[2] + rred[3];
  }
}

__global__ __launch_bounds__(256) void softmax_ge_kernel(
    const float* __restrict__ scores, const float* __restrict__ rowsum,
    float* __restrict__ ge)
{
  __shared__ float red[4];
  __shared__ float Msh, Zsh;
  int tid = threadIdx.x;

  float m = -1e30f;
  for (int n = tid; n < N_NODES; n += 256) m = fmaxf(m, scores[n]);
#pragma unroll
  for (int off = 32; off; off >>= 1) m = fmaxf(m, __shfl_down(m, off));
  if ((tid & 63) == 0) red[tid >> 6] = m;
  __syncthreads();
  if (tid == 0) Msh = fmaxf(fmaxf(red[0], red[1]), fmaxf(red[2], red[3]));
  __syncthreads();
  float M = Msh;

  float z = 0.0f;
  for (int n = tid; n < N_NODES; n += 256) z += expf(scores[n] - M);
#pragma unroll
  for (int off = 32; off; off >>= 1) z += __shfl_down(z, off);
  __syncthreads();
  if ((tid & 63) == 0) red[tid >> 6] = z;
  __syncthreads();
  if (tid == 0) Zsh = red[0] + red[1] + red[2] + red[3];
  __syncthreads();
  float Z = Zsh;

  for (int n = tid; n < N_NODES; n += 256)
    ge[n] = expf(scores[n] - M) / Z * rowsum[n];
}

__global__ void pooled_part_kernel(const float* __restrict__ x2, float* __restrict__ partial) {
  int f  = blockIdx.x * 256 + threadIdx.x;
  int r0 = blockIdx.y * 64;
  float s = 0.0f;
#pragma unroll 4
  for (int r = 0; r < 64; ++r) s += x2[(size_t)(r0 + r) * HID + f];
  partial[(size_t)blockIdx.y * HID + f] = s;
}

__global__ void pooled_final_kernel(const float* __restrict__ partial, float* __restrict__ pooled) {
  int f = blockIdx.x * 256 + threadIdx.x;
  float s = 0.0f;
#pragma unroll
  for (int r = 0; r < 32; ++r) s += partial[(size_t)r * HID + f];
  pooled[f] = s * (1.0f / N_NODES);
}

__global__ __launch_bounds__(256) void final_kernel(
    const float* __restrict__ pooled, const float* __restrict__ ge,
    const float* __restrict__ Wf, const float* __restrict__ bf,
    float* __restrict__ out)
{
  __shared__ float part[16][NCLS];
  int tid = threadIdx.x;
  int c = tid & 15, gg = tid >> 4;
  float s = 0.0f;
  for (int j = gg; j < HID; j += 16) {
    s = fmaf(pooled[j], Wf[(size_t)j * NCLS + c], s);
    s = fmaf(ge[j],     Wf[(size_t)(HID + j) * NCLS + c], s);
  }
  part[gg][c] = s;
  __syncthreads();
  if (gg == 0) {
    float t = 0.0f;
#pragma unroll
    for (int k = 0; k < 16; ++k) t += part[k][c];
    out[c] = t + bf[c];
  }
}

// ---------------------------------------------------------------------------
extern "C" void kernel_launch(void* const* d_in, const int* in_sizes, int n_in,
                              void* d_out, int out_size, void* d_ws, size_t ws_size,
                              hipStream_t stream) {
  const float* x   = (const float*)d_in[0];
  const int*   src = (const int*)  d_in[1];
  const int*   dst = (const int*)  d_in[2];
  const float* W1l = (const float*)d_in[3];
  const float* b1  = (const float*)d_in[4];
  const float* W1r = (const float*)d_in[5];
  const float* W2l = (const float*)d_in[6];
  const float* b2  = (const float*)d_in[7];
  const float* W2r = (const float*)d_in[8];
  const float* Wa  = (const float*)d_in[9];
  const float* ba  = (const float*)d_in[10];
  const float* Wf  = (const float*)d_in[11];
  const float* bf  = (const float*)d_in[12];
  float* out = (float*)d_out;

  const size_t MB = 1u << 20;
  char* w = (char*)d_ws;
  float* adj    = (float*)(w);              // 16MB; dead after cvt -> reused as x2
  float* x2     = (float*)(w);              // 16MB
  float* P      = (float*)(w + 16 * MB);    // up to 32MB fp32 partials
  short* adjb   = (short*)(w + 48 * MB);    // 8MB (perm cols)
  short* xb     = (short*)(w + 56 * MB);    // 2MB
  short* xT     = (short*)(w + 58 * MB);    // 2MB
  short* W1lT   = (short*)(w + 60 * MB);    // 2MB
  short* W1rT   = (short*)(w + 62 * MB);    // 2MB
  short* W2lT   = (short*)(w + 64 * MB);    // 8MB
  short* W2rT   = (short*)(w + 72 * MB);    // 8MB
  short* meanb  = (short*)(w + 80 * MB);    // 2MB
  short* x1b    = (short*)(w + 82 * MB);    // 8MB
  short* x1T    = (short*)(w + 90 * MB);    // 8MB; dead after mean2
  short* meanb2 = (short*)(w + 90 * MB);    // 8MB; overlays x1T (written after)
  float* cnt    = (float*)(w + 98 * MB);
  float* rsc    = cnt    + N_NODES;
  float* scores = rsc    + N_NODES;
  float* rowsum = scores + N_NODES;
  float* ge     = rowsum + N_NODES;
  float* pooled = ge     + N_NODES;
  float* partial= pooled + HID;             // 32*2048

  hipMemsetAsync(adj, 0, (size_t)N_NODES * N_NODES * sizeof(float), stream);
  hipMemsetAsync(cnt, 0, (size_t)N_NODES * sizeof(float), stream);

  build_adj_kernel<<<E_EDGES / 256, 256, 0, stream>>>(src, dst, adj, cnt);
  rscale_kernel<<<N_NODES / 256, 256, 0, stream>>>(cnt, rsc);

  // operand prep (all bf16 buffers K-permuted)
  cvt_f32_bf16<<<N_NODES * N_NODES / 4 / 256, 256, 0, stream>>>(adj, adjb, N_NODES * N_NODES / 4);
  cvt_perm_f32_bf16<<<N_NODES * IN_DIM / 4 / 256, 256, 0, stream>>>(x, xb, N_NODES * IN_DIM / 4);
  tr_f32_bf16_perm<<<dim3(IN_DIM / 32, N_NODES / 32), 256, 0, stream>>>(x,   xT,   N_NODES, IN_DIM);
  tr_f32_bf16_perm<<<dim3(HID / 32, IN_DIM / 32),     256, 0, stream>>>(W1l, W1lT, IN_DIM,  HID);
  tr_f32_bf16_perm<<<dim3(HID / 32, IN_DIM / 32),     256, 0, stream>>>(W1r, W1rT, IN_DIM,  HID);
  tr_f32_bf16_perm<<<dim3(HID / 32, HID / 32),        256, 0, stream>>>(W2l, W2lT, HID,     HID);
  tr_f32_bf16_perm<<<dim3(HID / 32, HID / 32),        256, 0, stream>>>(W2r, W2rT, HID,     HID);

  // mean1 = rowscale(adj @ x) : K=2048 in 4 z-slices -> P[4][2048][512]
  gemm_z<<<dim3(IN_DIM / 128, N_NODES / 128, 4), 256, 0, stream>>>(
      adjb, xT, N_NODES, 4, nullptr, nullptr, 0, P, N_NODES, IN_DIM);
  combine_kernel<<<(N_NODES * IN_DIM / 4) / 256, 256, 0, stream>>>(
      P, 4, (size_t)N_NODES * IN_DIM, rsc, 9, nullptr, 0, 0, meanb, nullptr);

  // x1 = relu(mean1 @ W1l + x @ W1r + b1) : z=0 pair1, z=1 pair2
  gemm_z<<<dim3(HID / 128, N_NODES / 128, 2), 256, 0, stream>>>(
      meanb, W1lT, IN_DIM, 1, xb, W1rT, IN_DIM, P, N_NODES, HID);
  combine_kernel<<<(N_NODES * HID / 4) / 256, 256, 0, stream>>>(
      P, 2, (size_t)N_NODES * HID, nullptr, 0, b1, HID - 1, 1, x1b, nullptr);

  // x1T (both-side permuted transpose)
  tr_bf16_perm2<<<dim3(HID / 32, N_NODES / 32), 256, 0, stream>>>(x1b, x1T, N_NODES, HID);

  // mean2 = rowscale(adj @ x1) : K=2048 in 2 z-slices
  gemm_z<<<dim3(HID / 128, N_NODES / 128, 2), 256, 0, stream>>>(
      adjb, x1T, N_NODES, 2, nullptr, nullptr, 0, P, N_NODES, HID);
  combine_kernel<<<(N_NODES * HID / 4) / 256, 256, 0, stream>>>(
      P, 2, (size_t)N_NODES * HID, rsc, 11, nullptr, 0, 0, meanb2, nullptr);

  // x2 = relu(mean2 @ W2l + x1 @ W2r + b2) : z=0 pair1, z=1 pair2 -> fp32
  gemm_z<<<dim3(HID / 128, N_NODES / 128, 2), 256, 0, stream>>>(
      meanb2, W2lT, HID, 1, x1b, W2rT, HID, P, N_NODES, HID);
  combine_kernel<<<(N_NODES * HID / 4) / 256, 256, 0, stream>>>(
      P, 2, (size_t)N_NODES * HID, nullptr, 0, b2, HID - 1, 1, nullptr, x2);

  // head
  scores_rowsum_kernel<<<N_NODES, 256, 0, stream>>>(x2, Wa, ba, scores, rowsum);
  softmax_ge_kernel<<<1, 256, 0, stream>>>(scores, rowsum, ge);
  pooled_part_kernel<<<dim3(HID / 256, 32), 256, 0, stream>>>(x2, partial);
  pooled_final_kernel<<<HID / 256, 256, 0, stream>>>(partial, pooled);
  final_kernel<<<1, 256, 0, stream>>>(pooled, ge, Wf, bf, out);
}

// Round 4
// 246.113 us; speedup vs baseline: 6.0394x; 1.2062x over previous
//
#include <hip/hip_runtime.h>
#include <hip/hip_bf16.h>
#include <cstddef>
#include <cstdint>

#define N_NODES 2048
#define E_EDGES 131072
#define IN_DIM  512
#define HID     2048
#define NCLS    16

typedef __bf16 bf16x8 __attribute__((ext_vector_type(8)));
typedef short  s16x4  __attribute__((ext_vector_type(4)));
typedef short  s16x8  __attribute__((ext_vector_type(8)));
typedef float  f32x4  __attribute__((ext_vector_type(4)));

__device__ __forceinline__ unsigned short f2bf(float f) {
  unsigned u = __builtin_bit_cast(unsigned, f);
  u = (u + 0x7FFFu + ((u >> 16) & 1u)) >> 16;
  return (unsigned short)u;
}

// K-permutation within each 32-col block: lane g's 8-elem MFMA fragment
// (k = g*4+{0..3}, g*4+16+{0..3}) becomes contiguous slots [8g,8g+8) -> one
// ds_read_b128 per fragment. pos32 is a bit 3-cycle; inverse = pos32 twice.
__device__ __forceinline__ int pos32(int k) {
  return (((k >> 2) & 3) << 3) | (((k >> 4) & 1) << 2) | (k & 3);
}

#define GLD16(gp, lp) __builtin_amdgcn_global_load_lds(                     \
    (__attribute__((address_space(1))) void*)(gp),                          \
    (__attribute__((address_space(3))) void*)(lp), 16, 0, 0)

// ---------------------------------------------------------------------------
// Dense adjacency build; columns stored K-PERMUTED (perm folded into atomics).
// ---------------------------------------------------------------------------
__global__ void build_adj_kernel(const int* __restrict__ src, const int* __restrict__ dst,
                                 float* __restrict__ adj, float* __restrict__ cnt) {
  int e = blockIdx.x * blockDim.x + threadIdx.x;
  if (e < E_EDGES) {
    int s = src[e], d = dst[e];
    int sp = (s & ~31) | pos32(s & 31);
    atomicAdd(&adj[(size_t)d * N_NODES + sp], 1.0f);
    atomicAdd(&cnt[d], 1.0f);
  }
}

__global__ void rscale_kernel(const float* __restrict__ cnt, float* __restrict__ rscale) {
  int i = blockIdx.x * blockDim.x + threadIdx.x;
  if (i < N_NODES) rscale[i] = 1.0f / fmaxf(cnt[i], 1.0f);
}

// ---------------------------------------------------------------------------
// Fused operand prep: one launch, blockIdx.x ranges select the sub-op.
//  [0,4096)        cvt adjf->adjb       (plain; adj already col-permuted)
//  [4096,5120)     cvt x->xb            (perm slots)
//  [5120,6144)     tr  x->xT            (16 x 64 tiles)
//  [6144,7168)     tr  W1l->W1lT        (64 x 16)
//  [7168,8192)     tr  W1r->W1rT        (64 x 16)
//  [8192,12288)    tr  W2l->W2lT        (64 x 64)
//  [12288,16384)   tr  W2r->W2rT        (64 x 64)
// Transposes: fp32 [R][C] -> bf16 [C][R], K-permuted slots over R.
// ---------------------------------------------------------------------------
__global__ __launch_bounds__(256) void prep_kernel(
    const float* __restrict__ adjf, short* __restrict__ adjb,
    const float* __restrict__ x,   short* __restrict__ xb,   short* __restrict__ xT,
    const float* __restrict__ W1l, short* __restrict__ W1lT,
    const float* __restrict__ W1r, short* __restrict__ W1rT,
    const float* __restrict__ W2l, short* __restrict__ W2lT,
    const float* __restrict__ W2r, short* __restrict__ W2rT)
{
  int bid = blockIdx.x, tid = threadIdx.x;
  if (bid < 4096) {                         // adj cvt (plain layout)
    size_t flat = ((size_t)bid * 256 + tid) * 4;
    float4 v = *reinterpret_cast<const float4*>(&adjf[flat]);
    s16x4 o;
    o[0] = (short)f2bf(v.x); o[1] = (short)f2bf(v.y);
    o[2] = (short)f2bf(v.z); o[3] = (short)f2bf(v.w);
    *reinterpret_cast<s16x4*>(&adjb[flat]) = o;
    return;
  }
  bid -= 4096;
  if (bid < 1024) {                         // x cvt, perm slots
    size_t flat = ((size_t)bid * 256 + tid) * 4;
    float4 v = *reinterpret_cast<const float4*>(&x[flat]);
    s16x4 o;
    o[0] = (short)f2bf(v.x); o[1] = (short)f2bf(v.y);
    o[2] = (short)f2bf(v.z); o[3] = (short)f2bf(v.w);
    size_t base = (flat & ~(size_t)31) | (size_t)pos32((int)(flat & 31));
    *reinterpret_cast<s16x4*>(&xb[base]) = o;
    return;
  }
  bid -= 1024;
  __shared__ float t[32][33];
  const float* in; short* outp; int R, C, bx, by;
  if (bid < 1024)      { in = x;   outp = xT;   R = N_NODES; C = IN_DIM; bx = bid & 15; by = bid >> 4; }
  else if (bid < 2048) { bid -= 1024; in = W1l; outp = W1lT; R = IN_DIM; C = HID; bx = bid & 63; by = bid >> 6; }
  else if (bid < 3072) { bid -= 2048; in = W1r; outp = W1rT; R = IN_DIM; C = HID; bx = bid & 63; by = bid >> 6; }
  else if (bid < 7168) { bid -= 3072; in = W2l; outp = W2lT; R = HID;    C = HID; bx = bid & 63; by = bid >> 6; }
  else                 { bid -= 7168; in = W2r; outp = W2rT; R = HID;    C = HID; bx = bid & 63; by = bid >> 6; }
  int c0 = bx * 32, r0 = by * 32;
  int tx = tid & 31, ty = tid >> 5;
#pragma unroll
  for (int i = 0; i < 4; ++i)
    t[ty + 8 * i][tx] = in[(size_t)(r0 + ty + 8 * i) * C + c0 + tx];
  __syncthreads();
  int ip = pos32(pos32(tx));   // inverse perm
#pragma unroll
  for (int i = 0; i < 4; ++i)
    outp[(size_t)(c0 + ty + 8 * i) * R + r0 + tx] = (short)f2bf(t[ip][ty + 8 * i]);
}

// ---------------------------------------------------------------------------
// bf16 MFMA GEMM, z-packed K/operand slices -> fp32 partials P[z][M][N].
// Block tile 128x128, 4 waves (2x2), wave tile 64x64, BK=32.
// z < n1: pair1 K-slice z of n1; z >= n1: pair2 K-slice (z-n1) of (gridDim.z-n1).
// ---------------------------------------------------------------------------
__global__ __launch_bounds__(256) void gemm_z(
    const short* __restrict__ A1, const short* __restrict__ B1, int K1, int n1,
    const short* __restrict__ A2, const short* __restrict__ B2, int K2,
    float* __restrict__ P, int M, int N)
{
  __shared__ short As[128 * 32];   // 8 KB
  __shared__ short Bs[128 * 32];   // 8 KB

  const int z = blockIdx.z;
  const short* A; const short* B; int lda, k0, kend;
  if (z < n1) { A = A1; B = B1; lda = K1; int ks = K1 / n1; k0 = z * ks; kend = k0 + ks; }
  else        { A = A2; B = B2; lda = K2; int n2 = gridDim.z - n1; int ks = K2 / n2;
                k0 = (z - n1) * ks; kend = k0 + ks; }
  float* Pz = P + (size_t)z * M * N;

  const int tid = threadIdx.x, wid = tid >> 6, lane = tid & 63;
  const int g = lane >> 4, r16 = lane & 15;
  const int wm = (wid >> 1) * 64, wn = (wid & 1) * 64;
  const int bm = blockIdx.y * 128, bn = blockIdx.x * 128;

  f32x4 acc[4][4];
#pragma unroll
  for (int mi = 0; mi < 4; ++mi)
#pragma unroll
    for (int ni = 0; ni < 4; ++ni)
#pragma unroll
      for (int r = 0; r < 4; ++r) acc[mi][ni][r] = 0.0f;

#pragma unroll 1
  for (int k = k0; k < kend; k += 32) {
    __syncthreads();   // previous tiles fully consumed
#pragma unroll
    for (int h = 0; h < 2; ++h) {   // stage A: 512 16B-units
      int U = h * 256 + wid * 64 + lane;
      int m = U >> 2, u = (U & 3) ^ (m & 3);
      GLD16(A + (size_t)(bm + m) * lda + k + u * 8, &As[(h * 256 + wid * 64) * 8]);
    }
#pragma unroll
    for (int h = 0; h < 2; ++h) {   // stage B: 512 16B-units
      int U = h * 256 + wid * 64 + lane;
      int n = U >> 2, u = (U & 3) ^ (n & 3);
      GLD16(B + (size_t)(bn + n) * lda + k + u * 8, &Bs[(h * 256 + wid * 64) * 8]);
    }
    __syncthreads();   // vmcnt(0): tiles resident

    bf16x8 a[4], b[4];
#pragma unroll
    for (int mi = 0; mi < 4; ++mi) {
      int m = wm + mi * 16 + r16;
      a[mi] = __builtin_bit_cast(bf16x8, *(const s16x8*)&As[m * 32 + ((g ^ (m & 3)) << 3)]);
    }
#pragma unroll
    for (int ni = 0; ni < 4; ++ni) {
      int n = wn + ni * 16 + r16;
      b[ni] = __builtin_bit_cast(bf16x8, *(const s16x8*)&Bs[n * 32 + ((g ^ (n & 3)) << 3)]);
    }
#pragma unroll
    for (int mi = 0; mi < 4; ++mi)
#pragma unroll
      for (int ni = 0; ni < 4; ++ni)
        acc[mi][ni] = __builtin_amdgcn_mfma_f32_16x16x32_bf16(a[mi], b[ni], acc[mi][ni], 0, 0, 0);
  }

#pragma unroll
  for (int mi = 0; mi < 4; ++mi)
#pragma unroll
    for (int r = 0; r < 4; ++r) {
      int row = bm + wm + mi * 16 + g * 4 + r;
#pragma unroll
      for (int ni = 0; ni < 4; ++ni) {
        int col = bn + wn + ni * 16 + r16;
        Pz[(size_t)row * N + col] = acc[mi][ni][r];
      }
    }
}

// ---------------------------------------------------------------------------
// Combine z-partials: sum, optional rscale[row]/bias[col]/relu; write fp32
// plain (may alias P slice 0: same-index read-then-write) and/or bf16 perm.
// ---------------------------------------------------------------------------
__global__ __launch_bounds__(256) void combine_kernel(
    const float* P, int nz, size_t MN,
    const float* rsc, int rshift,
    const float* bias, int cmask, int doRelu,
    short* outb, float* outf)
{
  size_t flat = ((size_t)blockIdx.x * 256 + threadIdx.x) * 4;
  if (flat >= MN) return;
  float4 s = *reinterpret_cast<const float4*>(&P[flat]);
#pragma unroll 1
  for (int zz = 1; zz < nz; ++zz) {
    float4 t = *reinterpret_cast<const float4*>(&P[(size_t)zz * MN + flat]);
    s.x += t.x; s.y += t.y; s.z += t.z; s.w += t.w;
  }
  if (rsc) {
    float sc = rsc[flat >> rshift];
    s.x *= sc; s.y *= sc; s.z *= sc; s.w *= sc;
  }
  if (bias) {
    float4 bv = *reinterpret_cast<const float4*>(&bias[flat & (size_t)cmask]);
    s.x += bv.x; s.y += bv.y; s.z += bv.z; s.w += bv.w;
  }
  if (doRelu) {
    s.x = fmaxf(s.x, 0.0f); s.y = fmaxf(s.y, 0.0f);
    s.z = fmaxf(s.z, 0.0f); s.w = fmaxf(s.w, 0.0f);
  }
  if (outf) *reinterpret_cast<float4*>(&outf[flat]) = s;
  if (outb) {
    s16x4 o;
    o[0] = (short)f2bf(s.x); o[1] = (short)f2bf(s.y);
    o[2] = (short)f2bf(s.z); o[3] = (short)f2bf(s.w);
    size_t base = (flat & ~(size_t)31) | (size_t)pos32((int)(flat & 31));
    *reinterpret_cast<s16x4*>(&outb[base]) = o;
  }
}

// ---------------------------------------------------------------------------
// x1 finisher: sum nz partials + bias + relu, write x1b (bf16, perm cols) AND
// x1T (bf16, transposed, perm slots) via 32x32 LDS tile. Grid (HID/32, N/32).
// ---------------------------------------------------------------------------
__global__ __launch_bounds__(256) void combine_tr_kernel(
    const float* __restrict__ P, int nz,
    const float* __restrict__ bias,
    short* __restrict__ xn, short* __restrict__ xnT)
{
  __shared__ float t[32][33];
  const size_t MN = (size_t)N_NODES * HID;
  int c0 = blockIdx.x * 32, r0 = blockIdx.y * 32;
  int tx = threadIdx.x & 31, ty = threadIdx.x >> 5;
  int colp = c0 + pos32(tx);
#pragma unroll
  for (int i = 0; i < 4; ++i) {
    int row = r0 + ty + 8 * i;
    size_t idx = (size_t)row * HID + c0 + tx;
    float v = P[idx];
#pragma unroll 1
    for (int zz = 1; zz < nz; ++zz) v += P[(size_t)zz * MN + idx];
    v += bias[c0 + tx];
    v = fmaxf(v, 0.0f);
    xn[(size_t)row * HID + colp] = (short)f2bf(v);
    t[ty + 8 * i][tx] = v;
  }
  __syncthreads();
  int ip = pos32(pos32(tx));   // inverse perm
#pragma unroll
  for (int i = 0; i < 4; ++i) {
    int cl = ty + 8 * i;
    xnT[(size_t)(c0 + cl) * N_NODES + r0 + tx] = (short)f2bf(t[ip][cl]);
  }
}

// ---------------------------------------------------------------------------
// Head part 1: per-row scores/rowsum (blocks [0,2048)) and per-col partial
// sums for pooled (blocks [2048,2304)).
// ---------------------------------------------------------------------------
__global__ __launch_bounds__(256) void scores_pooled_kernel(
    const float* __restrict__ x2, const float* __restrict__ Wa,
    const float* __restrict__ ba, float* __restrict__ scores,
    float* __restrict__ rowsum, float* __restrict__ partial)
{
  int bid = blockIdx.x, tid = threadIdx.x;
  if (bid < N_NODES) {
    const float* row = x2 + (size_t)bid * HID;
    float s = 0.0f, r = 0.0f;
    for (int f = tid; f < HID; f += 256) {
      float v = row[f];
      s = fmaf(v, Wa[f], s);
      r += v;
    }
#pragma unroll
    for (int off = 32; off; off >>= 1) {
      s += __shfl_down(s, off);
      r += __shfl_down(r, off);
    }
    __shared__ float sred[4], rred[4];
    if ((tid & 63) == 0) { sred[tid >> 6] = s; rred[tid >> 6] = r; }
    __syncthreads();
    if (tid == 0) {
      scores[bid] = sred[0] + sred[1] + sred[2] + sred[3] + ba[0];
      rowsum[bid] = rred[0] + rred[1] + rred[2] + rred[3];
    }
  } else {
    int q = bid - N_NODES;              // 0..255
    int f  = (q & 7) * 256 + tid;
    int r0 = (q >> 3) * 64;
    float s = 0.0f;
#pragma unroll 4
    for (int r = 0; r < 64; ++r) s += x2[(size_t)(r0 + r) * HID + f];
    partial[(size_t)(q >> 3) * HID + f] = s;
  }
}

// ---------------------------------------------------------------------------
// Head part 2 (single block, 1024 threads): softmax over scores -> ge (LDS),
// pooled from partial (LDS), final linear -> out[16].
// ---------------------------------------------------------------------------
__global__ __launch_bounds__(1024) void tail_kernel(
    const float* __restrict__ scores, const float* __restrict__ rowsum,
    const float* __restrict__ partial,
    const float* __restrict__ Wf, const float* __restrict__ bf,
    float* __restrict__ out)
{
  __shared__ float ge_s[N_NODES];
  __shared__ float pl[HID];
  __shared__ float part[64][NCLS];
  __shared__ float red[16];
  __shared__ float Msh, Zsh;
  int tid = threadIdx.x;

  float m = -1e30f;
  for (int n = tid; n < N_NODES; n += 1024) m = fmaxf(m, scores[n]);
#pragma unroll
  for (int off = 32; off; off >>= 1) m = fmaxf(m, __shfl_down(m, off));
  if ((tid & 63) == 0) red[tid >> 6] = m;
  __syncthreads();
  if (tid == 0) {
    float mm = red[0];
#pragma unroll
    for (int k = 1; k < 16; ++k) mm = fmaxf(mm, red[k]);
    Msh = mm;
  }
  __syncthreads();
  float M = Msh;

  float z = 0.0f;
  for (int n = tid; n < N_NODES; n += 1024) z += expf(scores[n] - M);
#pragma unroll
  for (int off = 32; off; off >>= 1) z += __shfl_down(z, off);
  __syncthreads();
  if ((tid & 63) == 0) red[tid >> 6] = z;
  __syncthreads();
  if (tid == 0) {
    float zz = 0.0f;
#pragma unroll
    for (int k = 0; k < 16; ++k) zz += red[k];
    Zsh = zz;
  }
  __syncthreads();
  float Z = Zsh;

  for (int n = tid; n < N_NODES; n += 1024)
    ge_s[n] = expf(scores[n] - M) / Z * rowsum[n];

  for (int f = tid; f < HID; f += 1024) {
    float s = 0.0f;
#pragma unroll
    for (int r = 0; r < 32; ++r) s += partial[(size_t)r * HID + f];
    pl[f] = s * (1.0f / N_NODES);
  }
  __syncthreads();

  int c = tid & 15, gg = tid >> 4;      // 64 groups of 16 classes
  float s = 0.0f;
  for (int j = gg; j < HID; j += 64) {
    s = fmaf(pl[j],   Wf[(size_t)j * NCLS + c], s);
    s = fmaf(ge_s[j], Wf[(size_t)(HID + j) * NCLS + c], s);
  }
  part[gg][c] = s;
  __syncthreads();
  if (tid < NCLS) {
    float tsum = 0.0f;
#pragma unroll
    for (int k = 0; k < 64; ++k) tsum += part[k][tid];
    out[tid] = tsum + bf[tid];
  }
}

// ---------------------------------------------------------------------------
extern "C" void kernel_launch(void* const* d_in, const int* in_sizes, int n_in,
                              void* d_out, int out_size, void* d_ws, size_t ws_size,
                              hipStream_t stream) {
  const float* x   = (const float*)d_in[0];
  const int*   src = (const int*)  d_in[1];
  const int*   dst = (const int*)  d_in[2];
  const float* W1l = (const float*)d_in[3];
  const float* b1  = (const float*)d_in[4];
  const float* W1r = (const float*)d_in[5];
  const float* W2l = (const float*)d_in[6];
  const float* b2  = (const float*)d_in[7];
  const float* W2r = (const float*)d_in[8];
  const float* Wa  = (const float*)d_in[9];
  const float* ba  = (const float*)d_in[10];
  const float* Wf  = (const float*)d_in[11];
  const float* bf  = (const float*)d_in[12];
  float* out = (float*)d_out;

  const size_t MB = 1u << 20;
  char* w = (char*)d_ws;
  // Lifetime-overlaid layout (~107 MB peak):
  float* P      = (float*)(w);              // 0-64MB: fp32 partials (<=4 slices)
  float* x2     = (float*)(w);              // alias P slice 0 (in-place combine)
  float* adjf   = (float*)(w + 16 * MB);    // 16-32MB temp; dead before GEMMs
  short* adjb   = (short*)(w + 64 * MB);    // 64-72; dead after mean2
  short* meanb2 = (short*)(w + 64 * MB);    //   overlay (written after mean2)
  short* W2lT   = (short*)(w + 72 * MB);    // 72-80
  short* W2rT   = (short*)(w + 80 * MB);    // 80-88
  short* x1b    = (short*)(w + 88 * MB);    // 88-96
  short* xb     = (short*)(w + 96 * MB);    // 96-98; dead after x1 gemm
  short* xT     = (short*)(w + 98 * MB);    // 98-100
  short* W1lT   = (short*)(w + 100 * MB);   // 100-102
  short* W1rT   = (short*)(w + 102 * MB);   // 102-104
  short* x1T    = (short*)(w + 96 * MB);    //   overlay 96-104 (after x1 gemm)
  short* meanb  = (short*)(w + 104 * MB);   // 104-106; dead after x1 gemm
  float* cnt    = (float*)(w + 106 * MB);
  float* rsc    = cnt    + N_NODES;
  float* scores = rsc    + N_NODES;
  float* rowsum = scores + N_NODES;
  float* partial= rowsum + N_NODES;         // 32*2048

  hipMemsetAsync(adjf, 0, (size_t)N_NODES * N_NODES * sizeof(float), stream);
  hipMemsetAsync(cnt, 0, (size_t)N_NODES * sizeof(float), stream);

  build_adj_kernel<<<E_EDGES / 256, 256, 0, stream>>>(src, dst, adjf, cnt);
  rscale_kernel<<<N_NODES / 256, 256, 0, stream>>>(cnt, rsc);

  prep_kernel<<<16384, 256, 0, stream>>>(adjf, adjb, x, xb, xT,
                                         W1l, W1lT, W1r, W1rT,
                                         W2l, W2lT, W2r, W2rT);

  // mean1 = rowscale(adj @ x): K=2048 in 8 z-slices (512 blocks, 2/CU)
  gemm_z<<<dim3(IN_DIM / 128, N_NODES / 128, 8), 256, 0, stream>>>(
      adjb, xT, N_NODES, 8, nullptr, nullptr, 0, P, N_NODES, IN_DIM);
  combine_kernel<<<(N_NODES * IN_DIM / 4) / 256, 256, 0, stream>>>(
      P, 8, (size_t)N_NODES * IN_DIM, rsc, 9, nullptr, 0, 0, meanb, nullptr);

  // x1 = relu(mean1 @ W1l + x @ W1r + b1): z=0 pair1, z=1 pair2 (512 blocks)
  gemm_z<<<dim3(HID / 128, N_NODES / 128, 2), 256, 0, stream>>>(
      meanb, W1lT, IN_DIM, 1, xb, W1rT, IN_DIM, P, N_NODES, HID);
  combine_tr_kernel<<<dim3(HID / 32, N_NODES / 32), 256, 0, stream>>>(
      P, 2, b1, x1b, x1T);

  // mean2 = rowscale(adj @ x1): K=2048 in 4 z-slices (1024 blocks, 4/CU)
  gemm_z<<<dim3(HID / 128, N_NODES / 128, 4), 256, 0, stream>>>(
      adjb, x1T, N_NODES, 4, nullptr, nullptr, 0, P, N_NODES, HID);
  combine_kernel<<<(N_NODES * HID / 4) / 256, 256, 0, stream>>>(
      P, 4, (size_t)N_NODES * HID, rsc, 11, nullptr, 0, 0, meanb2, nullptr);

  // x2 = relu(mean2 @ W2l + x1 @ W2r + b2): each pair split in 2 (1024 blocks)
  gemm_z<<<dim3(HID / 128, N_NODES / 128, 4), 256, 0, stream>>>(
      meanb2, W2lT, HID, 2, x1b, W2rT, HID, P, N_NODES, HID);
  combine_kernel<<<(N_NODES * HID / 4) / 256, 256, 0, stream>>>(
      P, 4, (size_t)N_NODES * HID, nullptr, 0, b2, HID - 1, 1, nullptr, x2);

  // head
  scores_pooled_kernel<<<N_NODES + 256, 256, 0, stream>>>(x2, Wa, ba, scores, rowsum, partial);
  tail_kernel<<<1, 1024, 0, stream>>>(scores, rowsum, partial, Wf, bf, out);
}

// Round 5
// 239.313 us; speedup vs baseline: 6.2110x; 1.0284x over previous
//
#include <hip/hip_runtime.h>
#include <hip/hip_bf16.h>
#include <cstddef>
#include <cstdint>

#define N_NODES 2048
#define E_EDGES 131072
#define IN_DIM  512
#define HID     2048
#define NCLS    16

typedef __bf16 bf16x8 __attribute__((ext_vector_type(8)));
typedef short  s16x4  __attribute__((ext_vector_type(4)));
typedef short  s16x8  __attribute__((ext_vector_type(8)));
typedef float  f32x4  __attribute__((ext_vector_type(4)));

__device__ __forceinline__ unsigned short f2bf(float f) {
  unsigned u = __builtin_bit_cast(unsigned, f);
  u = (u + 0x7FFFu + ((u >> 16) & 1u)) >> 16;
  return (unsigned short)u;
}

// K-permutation within each 32-col block: lane g's 8-elem MFMA fragment
// (k = g*4+{0..3}, g*4+16+{0..3}) becomes contiguous slots [8g,8g+8) -> one
// ds_read_b128 per fragment. pos32 is a bit 3-cycle; inverse = pos32 twice.
__device__ __forceinline__ int pos32(int k) {
  return (((k >> 2) & 3) << 3) | (((k >> 4) & 1) << 2) | (k & 3);
}

#define GLD16(gp, lp) __builtin_amdgcn_global_load_lds(                     \
    (__attribute__((address_space(1))) void*)(gp),                          \
    (__attribute__((address_space(3))) void*)(lp), 16, 0, 0)

// ---------------------------------------------------------------------------
// Dense adjacency build; columns stored K-PERMUTED (perm folded into atomics).
// ---------------------------------------------------------------------------
__global__ void build_adj_kernel(const int* __restrict__ src, const int* __restrict__ dst,
                                 float* __restrict__ adj, float* __restrict__ cnt) {
  int e = blockIdx.x * blockDim.x + threadIdx.x;
  if (e < E_EDGES) {
    int s = src[e], d = dst[e];
    int sp = (s & ~31) | pos32(s & 31);
    atomicAdd(&adj[(size_t)d * N_NODES + sp], 1.0f);
    atomicAdd(&cnt[d], 1.0f);
  }
}

__global__ void rscale_kernel(const float* __restrict__ cnt, float* __restrict__ rscale) {
  int i = blockIdx.x * blockDim.x + threadIdx.x;
  if (i < N_NODES) rscale[i] = 1.0f / fmaxf(cnt[i], 1.0f);
}

// ---------------------------------------------------------------------------
// Fused operand prep: one launch, blockIdx.x ranges select the sub-op.
// ---------------------------------------------------------------------------
__global__ __launch_bounds__(256) void prep_kernel(
    const float* __restrict__ adjf, short* __restrict__ adjb,
    const float* __restrict__ x,   short* __restrict__ xb,   short* __restrict__ xT,
    const float* __restrict__ W1l, short* __restrict__ W1lT,
    const float* __restrict__ W1r, short* __restrict__ W1rT,
    const float* __restrict__ W2l, short* __restrict__ W2lT,
    const float* __restrict__ W2r, short* __restrict__ W2rT)
{
  int bid = blockIdx.x, tid = threadIdx.x;
  if (bid < 4096) {                         // adj cvt (plain layout)
    size_t flat = ((size_t)bid * 256 + tid) * 4;
    float4 v = *reinterpret_cast<const float4*>(&adjf[flat]);
    s16x4 o;
    o[0] = (short)f2bf(v.x); o[1] = (short)f2bf(v.y);
    o[2] = (short)f2bf(v.z); o[3] = (short)f2bf(v.w);
    *reinterpret_cast<s16x4*>(&adjb[flat]) = o;
    return;
  }
  bid -= 4096;
  if (bid < 1024) {                         // x cvt, perm slots
    size_t flat = ((size_t)bid * 256 + tid) * 4;
    float4 v = *reinterpret_cast<const float4*>(&x[flat]);
    s16x4 o;
    o[0] = (short)f2bf(v.x); o[1] = (short)f2bf(v.y);
    o[2] = (short)f2bf(v.z); o[3] = (short)f2bf(v.w);
    size_t base = (flat & ~(size_t)31) | (size_t)pos32((int)(flat & 31));
    *reinterpret_cast<s16x4*>(&xb[base]) = o;
    return;
  }
  bid -= 1024;
  __shared__ float t[32][33];
  const float* in; short* outp; int R, C, bx, by;
  if (bid < 1024)      { in = x;   outp = xT;   R = N_NODES; C = IN_DIM; bx = bid & 15; by = bid >> 4; }
  else if (bid < 2048) { bid -= 1024; in = W1l; outp = W1lT; R = IN_DIM; C = HID; bx = bid & 63; by = bid >> 6; }
  else if (bid < 3072) { bid -= 2048; in = W1r; outp = W1rT; R = IN_DIM; C = HID; bx = bid & 63; by = bid >> 6; }
  else if (bid < 7168) { bid -= 3072; in = W2l; outp = W2lT; R = HID;    C = HID; bx = bid & 63; by = bid >> 6; }
  else                 { bid -= 7168; in = W2r; outp = W2rT; R = HID;    C = HID; bx = bid & 63; by = bid >> 6; }
  int c0 = bx * 32, r0 = by * 32;
  int tx = tid & 31, ty = tid >> 5;
#pragma unroll
  for (int i = 0; i < 4; ++i)
    t[ty + 8 * i][tx] = in[(size_t)(r0 + ty + 8 * i) * C + c0 + tx];
  __syncthreads();
  int ip = pos32(pos32(tx));   // inverse perm
#pragma unroll
  for (int i = 0; i < 4; ++i)
    outp[(size_t)(c0 + ty + 8 * i) * R + r0 + tx] = (short)f2bf(t[ip][ty + 8 * i]);
}

// ---------------------------------------------------------------------------
// bf16 MFMA GEMM with double-buffered LDS prefetch pipeline.
// Block tile 128x128, 4 waves (2x2), wave tile 64x64, BK=32.
// Each z-slice covers slice z (of nz) of pair1's K AND pair2's K (if A2).
// Loop: STAGE(next tile) -> ds_read+MFMA(current) -> __syncthreads()
// (implicit vmcnt(0) drains AFTER compute: loads fly under the MFMAs).
// ---------------------------------------------------------------------------
__global__ __launch_bounds__(256) void gemm_z(
    const short* __restrict__ A1, const short* __restrict__ B1, int K1,
    const short* __restrict__ A2, const short* __restrict__ B2, int K2,
    int nz, float* __restrict__ P, int M, int N)
{
  __shared__ short As[2][128 * 32];   // 2 x 8 KB
  __shared__ short Bs[2][128 * 32];   // 2 x 8 KB

  const int tid = threadIdx.x, wid = tid >> 6, lane = tid & 63;
  const int g = lane >> 4, r16 = lane & 15;
  const int wm = (wid >> 1) * 64, wn = (wid & 1) * 64;
  const int bm = blockIdx.y * 128, bn = blockIdx.x * 128;
  const int z = blockIdx.z;

  const int s1  = K1 / nz / 32;                 // k-steps for pair1 slice
  const int s2  = A2 ? K2 / nz / 32 : 0;        // k-steps for pair2 slice
  const int k01 = z * (K1 / nz);
  const int k02 = A2 ? z * (K2 / nz) : 0;
  const int total = s1 + s2;
  float* Pz = P + (size_t)z * M * N;

  auto STAGE = [&](int t, int buf) {
    const short* A; const short* B; int lda, k;
    if (t < s1) { A = A1; B = B1; lda = K1; k = k01 + t * 32; }
    else        { A = A2; B = B2; lda = K2; k = k02 + (t - s1) * 32; }
#pragma unroll
    for (int h = 0; h < 2; ++h) {     // A: 512 16B-units
      int U = h * 256 + wid * 64 + lane;
      int m = U >> 2, u = (U & 3) ^ (m & 3);
      GLD16(A + (size_t)(bm + m) * lda + k + u * 8, &As[buf][(h * 256 + wid * 64) * 8]);
    }
#pragma unroll
    for (int h = 0; h < 2; ++h) {     // B: 512 16B-units
      int U = h * 256 + wid * 64 + lane;
      int n = U >> 2, u = (U & 3) ^ (n & 3);
      GLD16(B + (size_t)(bn + n) * lda + k + u * 8, &Bs[buf][(h * 256 + wid * 64) * 8]);
    }
  };

  f32x4 acc[4][4];
#pragma unroll
  for (int mi = 0; mi < 4; ++mi)
#pragma unroll
    for (int ni = 0; ni < 4; ++ni)
#pragma unroll
      for (int r = 0; r < 4; ++r) acc[mi][ni][r] = 0.0f;

  STAGE(0, 0);
  __syncthreads();                     // tile 0 resident

#pragma unroll 1
  for (int t = 0; t < total; ++t) {
    const int cur = t & 1;
    if (t + 1 < total) STAGE(t + 1, cur ^ 1);   // issue next-tile loads

    bf16x8 a[4], b[4];
#pragma unroll
    for (int mi = 0; mi < 4; ++mi) {
      int m = wm + mi * 16 + r16;
      a[mi] = __builtin_bit_cast(bf16x8, *(const s16x8*)&As[cur][m * 32 + ((g ^ (m & 3)) << 3)]);
    }
#pragma unroll
    for (int ni = 0; ni < 4; ++ni) {
      int n = wn + ni * 16 + r16;
      b[ni] = __builtin_bit_cast(bf16x8, *(const s16x8*)&Bs[cur][n * 32 + ((g ^ (n & 3)) << 3)]);
    }
#pragma unroll
    for (int mi = 0; mi < 4; ++mi)
#pragma unroll
      for (int ni = 0; ni < 4; ++ni)
        acc[mi][ni] = __builtin_amdgcn_mfma_f32_16x16x32_bf16(a[mi], b[ni], acc[mi][ni], 0, 0, 0);

    __syncthreads();   // drains vmcnt(0) (next tile) + all waves done with cur
  }

#pragma unroll
  for (int mi = 0; mi < 4; ++mi)
#pragma unroll
    for (int r = 0; r < 4; ++r) {
      int row = bm + wm + mi * 16 + g * 4 + r;
#pragma unroll
      for (int ni = 0; ni < 4; ++ni) {
        int col = bn + wn + ni * 16 + r16;
        Pz[(size_t)row * N + col] = acc[mi][ni][r];
      }
    }
}

// ---------------------------------------------------------------------------
// Combine z-partials: sum, optional rscale[row]/bias[col]/relu; write fp32
// plain (may alias P slice 0: same-index read-then-write) and/or bf16 perm.
// ---------------------------------------------------------------------------
__global__ __launch_bounds__(256) void combine_kernel(
    const float* P, int nz, size_t MN,
    const float* rsc, int rshift,
    const float* bias, int cmask, int doRelu,
    short* outb, float* outf)
{
  size_t flat = ((size_t)blockIdx.x * 256 + threadIdx.x) * 4;
  if (flat >= MN) return;
  float4 s = *reinterpret_cast<const float4*>(&P[flat]);
#pragma unroll 1
  for (int zz = 1; zz < nz; ++zz) {
    float4 t = *reinterpret_cast<const float4*>(&P[(size_t)zz * MN + flat]);
    s.x += t.x; s.y += t.y; s.z += t.z; s.w += t.w;
  }
  if (rsc) {
    float sc = rsc[flat >> rshift];
    s.x *= sc; s.y *= sc; s.z *= sc; s.w *= sc;
  }
  if (bias) {
    float4 bv = *reinterpret_cast<const float4*>(&bias[flat & (size_t)cmask]);
    s.x += bv.x; s.y += bv.y; s.z += bv.z; s.w += bv.w;
  }
  if (doRelu) {
    s.x = fmaxf(s.x, 0.0f); s.y = fmaxf(s.y, 0.0f);
    s.z = fmaxf(s.z, 0.0f); s.w = fmaxf(s.w, 0.0f);
  }
  if (outf) *reinterpret_cast<float4*>(&outf[flat]) = s;
  if (outb) {
    s16x4 o;
    o[0] = (short)f2bf(s.x); o[1] = (short)f2bf(s.y);
    o[2] = (short)f2bf(s.z); o[3] = (short)f2bf(s.w);
    size_t base = (flat & ~(size_t)31) | (size_t)pos32((int)(flat & 31));
    *reinterpret_cast<s16x4*>(&outb[base]) = o;
  }
}

// ---------------------------------------------------------------------------
// x1 finisher: sum nz partials + bias + relu, write x1b (bf16, perm cols) AND
// x1T (bf16, transposed, perm slots) via 32x32 LDS tile. Grid (HID/32, N/32).
// ---------------------------------------------------------------------------
__global__ __launch_bounds__(256) void combine_tr_kernel(
    const float* __restrict__ P, int nz,
    const float* __restrict__ bias,
    short* __restrict__ xn, short* __restrict__ xnT)
{
  __shared__ float t[32][33];
  const size_t MN = (size_t)N_NODES * HID;
  int c0 = blockIdx.x * 32, r0 = blockIdx.y * 32;
  int tx = threadIdx.x & 31, ty = threadIdx.x >> 5;
  int colp = c0 + pos32(tx);
#pragma unroll
  for (int i = 0; i < 4; ++i) {
    int row = r0 + ty + 8 * i;
    size_t idx = (size_t)row * HID + c0 + tx;
    float v = P[idx];
#pragma unroll 1
    for (int zz = 1; zz < nz; ++zz) v += P[(size_t)zz * MN + idx];
    v += bias[c0 + tx];
    v = fmaxf(v, 0.0f);
    xn[(size_t)row * HID + colp] = (short)f2bf(v);
    t[ty + 8 * i][tx] = v;
  }
  __syncthreads();
  int ip = pos32(pos32(tx));   // inverse perm
#pragma unroll
  for (int i = 0; i < 4; ++i) {
    int cl = ty + 8 * i;
    xnT[(size_t)(c0 + cl) * N_NODES + r0 + tx] = (short)f2bf(t[ip][cl]);
  }
}

// ---------------------------------------------------------------------------
// Head part 1: per-row scores/rowsum (blocks [0,2048)) and per-col partial
// sums for pooled (blocks [2048,2304)).
// ---------------------------------------------------------------------------
__global__ __launch_bounds__(256) void scores_pooled_kernel(
    const float* __restrict__ x2, const float* __restrict__ Wa,
    const float* __restrict__ ba, float* __restrict__ scores,
    float* __restrict__ rowsum, float* __restrict__ partial)
{
  int bid = blockIdx.x, tid = threadIdx.x;
  if (bid < N_NODES) {
    const float* row = x2 + (size_t)bid * HID;
    float s = 0.0f, r = 0.0f;
    for (int f = tid; f < HID; f += 256) {
      float v = row[f];
      s = fmaf(v, Wa[f], s);
      r += v;
    }
#pragma unroll
    for (int off = 32; off; off >>= 1) {
      s += __shfl_down(s, off);
      r += __shfl_down(r, off);
    }
    __shared__ float sred[4], rred[4];
    if ((tid & 63) == 0) { sred[tid >> 6] = s; rred[tid >> 6] = r; }
    __syncthreads();
    if (tid == 0) {
      scores[bid] = sred[0] + sred[1] + sred[2] + sred[3] + ba[0];
      rowsum[bid] = rred[0] + rred[1] + rred[2] + rred[3];
    }
  } else {
    int q = bid - N_NODES;              // 0..255
    int f  = (q & 7) * 256 + tid;
    int r0 = (q >> 3) * 64;
    float s = 0.0f;
#pragma unroll 4
    for (int r = 0; r < 64; ++r) s += x2[(size_t)(r0 + r) * HID + f];
    partial[(size_t)(q >> 3) * HID + f] = s;
  }
}

// ---------------------------------------------------------------------------
// Head part 2 (single block, 1024 threads): softmax over scores -> ge (LDS),
// pooled from partial (LDS), final linear -> out[16].
// ---------------------------------------------------------------------------
__global__ __launch_bounds__(1024) void tail_kernel(
    const float* __restrict__ scores, const float* __restrict__ rowsum,
    const float* __restrict__ partial,
    const float* __restrict__ Wf, const float* __restrict__ bf,
    float* __restrict__ out)
{
  __shared__ float ge_s[N_NODES];
  __shared__ float pl[HID];
  __shared__ float part[64][NCLS];
  __shared__ float red[16];
  __shared__ float Msh, Zsh;
  int tid = threadIdx.x;

  float m = -1e30f;
  for (int n = tid; n < N_NODES; n += 1024) m = fmaxf(m, scores[n]);
#pragma unroll
  for (int off = 32; off; off >>= 1) m = fmaxf(m, __shfl_down(m, off));
  if ((tid & 63) == 0) red[tid >> 6] = m;
  __syncthreads();
  if (tid == 0) {
    float mm = red[0];
#pragma unroll
    for (int k = 1; k < 16; ++k) mm = fmaxf(mm, red[k]);
    Msh = mm;
  }
  __syncthreads();
  float M = Msh;

  float z = 0.0f;
  for (int n = tid; n < N_NODES; n += 1024) z += expf(scores[n] - M);
#pragma unroll
  for (int off = 32; off; off >>= 1) z += __shfl_down(z, off);
  __syncthreads();
  if ((tid & 63) == 0) red[tid >> 6] = z;
  __syncthreads();
  if (tid == 0) {
    float zz = 0.0f;
#pragma unroll
    for (int k = 0; k < 16; ++k) zz += red[k];
    Zsh = zz;
  }
  __syncthreads();
  float Z = Zsh;

  for (int n = tid; n < N_NODES; n += 1024)
    ge_s[n] = expf(scores[n] - M) / Z * rowsum[n];

  for (int f = tid; f < HID; f += 1024) {
    float s = 0.0f;
#pragma unroll
    for (int r = 0; r < 32; ++r) s += partial[(size_t)r * HID + f];
    pl[f] = s * (1.0f / N_NODES);
  }
  __syncthreads();

  int c = tid & 15, gg = tid >> 4;      // 64 groups of 16 classes
  float s = 0.0f;
  for (int j = gg; j < HID; j += 64) {
    s = fmaf(pl[j],   Wf[(size_t)j * NCLS + c], s);
    s = fmaf(ge_s[j], Wf[(size_t)(HID + j) * NCLS + c], s);
  }
  part[gg][c] = s;
  __syncthreads();
  if (tid < NCLS) {
    float tsum = 0.0f;
#pragma unroll
    for (int k = 0; k < 64; ++k) tsum += part[k][tid];
    out[tid] = tsum + bf[tid];
  }
}

// ---------------------------------------------------------------------------
extern "C" void kernel_launch(void* const* d_in, const int* in_sizes, int n_in,
                              void* d_out, int out_size, void* d_ws, size_t ws_size,
                              hipStream_t stream) {
  const float* x   = (const float*)d_in[0];
  const int*   src = (const int*)  d_in[1];
  const int*   dst = (const int*)  d_in[2];
  const float* W1l = (const float*)d_in[3];
  const float* b1  = (const float*)d_in[4];
  const float* W1r = (const float*)d_in[5];
  const float* W2l = (const float*)d_in[6];
  const float* b2  = (const float*)d_in[7];
  const float* W2r = (const float*)d_in[8];
  const float* Wa  = (const float*)d_in[9];
  const float* ba  = (const float*)d_in[10];
  const float* Wf  = (const float*)d_in[11];
  const float* bf  = (const float*)d_in[12];
  float* out = (float*)d_out;

  const size_t MB = 1u << 20;
  char* w = (char*)d_ws;
  // Lifetime-overlaid layout (~107 MB peak):
  float* P      = (float*)(w);              // 0-64MB: fp32 partials
  float* x2     = (float*)(w);              // alias P slice 0 (in-place combine)
  float* adjf   = (float*)(w + 16 * MB);    // 16-32MB temp; dead before GEMMs
  short* adjb   = (short*)(w + 64 * MB);    // 64-72; dead after mean2
  short* meanb2 = (short*)(w + 64 * MB);    //   overlay (written after mean2)
  short* W2lT   = (short*)(w + 72 * MB);    // 72-80
  short* W2rT   = (short*)(w + 80 * MB);    // 80-88
  short* x1b    = (short*)(w + 88 * MB);    // 88-96
  short* xb     = (short*)(w + 96 * MB);    // 96-98; dead after x1 gemm
  short* xT     = (short*)(w + 98 * MB);    // 98-100
  short* W1lT   = (short*)(w + 100 * MB);   // 100-102
  short* W1rT   = (short*)(w + 102 * MB);   // 102-104
  short* x1T    = (short*)(w + 96 * MB);    //   overlay 96-104 (after x1 gemm)
  short* meanb  = (short*)(w + 104 * MB);   // 104-106; dead after x1 gemm
  float* cnt    = (float*)(w + 106 * MB);
  float* rsc    = cnt    + N_NODES;
  float* scores = rsc    + N_NODES;
  float* rowsum = scores + N_NODES;
  float* partial= rowsum + N_NODES;         // 32*2048

  hipMemsetAsync(adjf, 0, (size_t)N_NODES * N_NODES * sizeof(float), stream);
  hipMemsetAsync(cnt, 0, (size_t)N_NODES * sizeof(float), stream);

  build_adj_kernel<<<E_EDGES / 256, 256, 0, stream>>>(src, dst, adjf, cnt);
  rscale_kernel<<<N_NODES / 256, 256, 0, stream>>>(cnt, rsc);

  prep_kernel<<<16384, 256, 0, stream>>>(adjf, adjb, x, xb, xT,
                                         W1l, W1lT, W1r, W1rT,
                                         W2l, W2lT, W2r, W2rT);

  // mean1 = rowscale(adj @ x): K=2048, nz=8 (512 blocks, 8 steps each)
  gemm_z<<<dim3(IN_DIM / 128, N_NODES / 128, 8), 256, 0, stream>>>(
      adjb, xT, N_NODES, nullptr, nullptr, 0, 8, P, N_NODES, IN_DIM);
  combine_kernel<<<(N_NODES * IN_DIM / 4) / 256, 256, 0, stream>>>(
      P, 8, (size_t)N_NODES * IN_DIM, rsc, 9, nullptr, 0, 0, meanb, nullptr);

  // x1 = relu(mean1 @ W1l + x @ W1r + b1): nz=2 pair-fused (512 blocks, 16 steps)
  gemm_z<<<dim3(HID / 128, N_NODES / 128, 2), 256, 0, stream>>>(
      meanb, W1lT, IN_DIM, xb, W1rT, IN_DIM, 2, P, N_NODES, HID);
  combine_tr_kernel<<<dim3(HID / 32, N_NODES / 32), 256, 0, stream>>>(
      P, 2, b1, x1b, x1T);

  // mean2 = rowscale(adj @ x1): K=2048, nz=2 (512 blocks, 32 steps, P 32MB)
  gemm_z<<<dim3(HID / 128, N_NODES / 128, 2), 256, 0, stream>>>(
      adjb, x1T, N_NODES, nullptr, nullptr, 0, 2, P, N_NODES, HID);
  combine_kernel<<<(N_NODES * HID / 4) / 256, 256, 0, stream>>>(
      P, 2, (size_t)N_NODES * HID, rsc, 11, nullptr, 0, 0, meanb2, nullptr);

  // x2 = relu(mean2 @ W2l + x1 @ W2r + b2): nz=2 pair-fused (512 blocks, 64 steps)
  gemm_z<<<dim3(HID / 128, N_NODES / 128, 2), 256, 0, stream>>>(
      meanb2, W2lT, HID, x1b, W2rT, HID, 2, P, N_NODES, HID);
  combine_kernel<<<(N_NODES * HID / 4) / 256, 256, 0, stream>>>(
      P, 2, (size_t)N_NODES * HID, nullptr, 0, b2, HID - 1, 1, nullptr, x2);

  // head
  scores_pooled_kernel<<<N_NODES + 256, 256, 0, stream>>>(x2, Wa, ba, scores, rowsum, partial);
  tail_kernel<<<1, 1024, 0, stream>>>(scores, rowsum, partial, Wf, bf, out);
}

// Round 6
// 238.006 us; speedup vs baseline: 6.2451x; 1.0055x over previous
//
#include <hip/hip_runtime.h>
#include <hip/hip_bf16.h>
#include <cstddef>
#include <cstdint>

#define N_NODES 2048
#define E_EDGES 131072
#define IN_DIM  512
#define HID     2048
#define NCLS    16

typedef __bf16 bf16x8 __attribute__((ext_vector_type(8)));
typedef short  s16x4  __attribute__((ext_vector_type(4)));
typedef short  s16x8  __attribute__((ext_vector_type(8)));
typedef float  f32x4  __attribute__((ext_vector_type(4)));

__device__ __forceinline__ unsigned short f2bf(float f) {
  unsigned u = __builtin_bit_cast(unsigned, f);
  u = (u + 0x7FFFu + ((u >> 16) & 1u)) >> 16;
  return (unsigned short)u;
}

// K-permutation within each 32-col block: lane g's 8-elem MFMA fragment
// (k = g*4+{0..3}, g*4+16+{0..3}) becomes contiguous slots [8g,8g+8) -> one
// ds_read_b128 per fragment. pos32 is a bit 3-cycle; inverse = pos32 twice.
__device__ __forceinline__ int pos32(int k) {
  return (((k >> 2) & 3) << 3) | (((k >> 4) & 1) << 2) | (k & 3);
}

#define GLD16(gp, lp) __builtin_amdgcn_global_load_lds(                     \
    (__attribute__((address_space(1))) void*)(gp),                          \
    (__attribute__((address_space(3))) void*)(lp), 16, 0, 0)

#define WAITVM(N) asm volatile("s_waitcnt vmcnt(" #N ")" ::: "memory")

// ---------------------------------------------------------------------------
// Dense adjacency build; columns stored K-PERMUTED (perm folded into atomics).
// ---------------------------------------------------------------------------
__global__ void build_adj_kernel(const int* __restrict__ src, const int* __restrict__ dst,
                                 float* __restrict__ adj, float* __restrict__ cnt) {
  int e = blockIdx.x * blockDim.x + threadIdx.x;
  if (e < E_EDGES) {
    int s = src[e], d = dst[e];
    int sp = (s & ~31) | pos32(s & 31);
    atomicAdd(&adj[(size_t)d * N_NODES + sp], 1.0f);
    atomicAdd(&cnt[d], 1.0f);
  }
}

__global__ void rscale_kernel(const float* __restrict__ cnt, float* __restrict__ rscale) {
  int i = blockIdx.x * blockDim.x + threadIdx.x;
  if (i < N_NODES) rscale[i] = 1.0f / fmaxf(cnt[i], 1.0f);
}

// ---------------------------------------------------------------------------
// Fused operand prep: one launch, blockIdx.x ranges select the sub-op.
// ---------------------------------------------------------------------------
__global__ __launch_bounds__(256) void prep_kernel(
    const float* __restrict__ adjf, short* __restrict__ adjb,
    const float* __restrict__ x,   short* __restrict__ xb,   short* __restrict__ xT,
    const float* __restrict__ W1l, short* __restrict__ W1lT,
    const float* __restrict__ W1r, short* __restrict__ W1rT,
    const float* __restrict__ W2l, short* __restrict__ W2lT,
    const float* __restrict__ W2r, short* __restrict__ W2rT)
{
  int bid = blockIdx.x, tid = threadIdx.x;
  if (bid < 4096) {                         // adj cvt (plain layout)
    size_t flat = ((size_t)bid * 256 + tid) * 4;
    float4 v = *reinterpret_cast<const float4*>(&adjf[flat]);
    s16x4 o;
    o[0] = (short)f2bf(v.x); o[1] = (short)f2bf(v.y);
    o[2] = (short)f2bf(v.z); o[3] = (short)f2bf(v.w);
    *reinterpret_cast<s16x4*>(&adjb[flat]) = o;
    return;
  }
  bid -= 4096;
  if (bid < 1024) {                         // x cvt, perm slots
    size_t flat = ((size_t)bid * 256 + tid) * 4;
    float4 v = *reinterpret_cast<const float4*>(&x[flat]);
    s16x4 o;
    o[0] = (short)f2bf(v.x); o[1] = (short)f2bf(v.y);
    o[2] = (short)f2bf(v.z); o[3] = (short)f2bf(v.w);
    size_t base = (flat & ~(size_t)31) | (size_t)pos32((int)(flat & 31));
    *reinterpret_cast<s16x4*>(&xb[base]) = o;
    return;
  }
  bid -= 1024;
  __shared__ float t[32][33];
  const float* in; short* outp; int R, C, bx, by;
  if (bid < 1024)      { in = x;   outp = xT;   R = N_NODES; C = IN_DIM; bx = bid & 15; by = bid >> 4; }
  else if (bid < 2048) { bid -= 1024; in = W1l; outp = W1lT; R = IN_DIM; C = HID; bx = bid & 63; by = bid >> 6; }
  else if (bid < 3072) { bid -= 2048; in = W1r; outp = W1rT; R = IN_DIM; C = HID; bx = bid & 63; by = bid >> 6; }
  else if (bid < 7168) { bid -= 3072; in = W2l; outp = W2lT; R = HID;    C = HID; bx = bid & 63; by = bid >> 6; }
  else                 { bid -= 7168; in = W2r; outp = W2rT; R = HID;    C = HID; bx = bid & 63; by = bid >> 6; }
  int c0 = bx * 32, r0 = by * 32;
  int tx = tid & 31, ty = tid >> 5;
#pragma unroll
  for (int i = 0; i < 4; ++i)
    t[ty + 8 * i][tx] = in[(size_t)(r0 + ty + 8 * i) * C + c0 + tx];
  __syncthreads();
  int ip = pos32(pos32(tx));   // inverse perm
#pragma unroll
  for (int i = 0; i < 4; ++i)
    outp[(size_t)(c0 + ty + 8 * i) * R + r0 + tx] = (short)f2bf(t[ip][ty + 8 * i]);
}

// ---------------------------------------------------------------------------
// bf16 MFMA GEMM with 4-deep LDS pipeline + counted vmcnt (T3/T4).
// Block tile 128x128, 4 waves (2x2), wave tile 64x64, BK=32.
// Each z-slice covers slice z (of nz) of pair1's K AND pair2's K (if A2).
// Iter t: vmcnt(8) [tile t resident, 2 tiles in flight] -> s_barrier ->
// STAGE(t+3) -> ds_read+MFMA(t). Buffer (t+3)&3 is safe to overwrite: all
// waves passed barrier(t), so compute(t-1) reads of that buffer are done;
// its next read (iter t+3) is protected by that iter's vmcnt+barrier.
// Each wave issues exactly 4 global_load_lds per STAGE -> vmcnt arithmetic.
// ---------------------------------------------------------------------------
__global__ __launch_bounds__(256) void gemm_z(
    const short* __restrict__ A1, const short* __restrict__ B1, int K1,
    const short* __restrict__ A2, const short* __restrict__ B2, int K2,
    int nz, float* __restrict__ P, int M, int N)
{
  __shared__ short As[4][128 * 32];   // 4 x 8 KB
  __shared__ short Bs[4][128 * 32];   // 4 x 8 KB

  const int tid = threadIdx.x, wid = tid >> 6, lane = tid & 63;
  const int g = lane >> 4, r16 = lane & 15;
  const int wm = (wid >> 1) * 64, wn = (wid & 1) * 64;
  const int bm = blockIdx.y * 128, bn = blockIdx.x * 128;
  const int z = blockIdx.z;

  const int s1  = K1 / nz / 32;                 // k-steps for pair1 slice
  const int s2  = A2 ? K2 / nz / 32 : 0;        // k-steps for pair2 slice
  const int k01 = z * (K1 / nz);
  const int k02 = A2 ? z * (K2 / nz) : 0;
  const int total = s1 + s2;                    // >= 8 for all call sites
  float* Pz = P + (size_t)z * M * N;

  auto STAGE = [&](int t, int buf) {
    const short* A; const short* B; int lda, k;
    if (t < s1) { A = A1; B = B1; lda = K1; k = k01 + t * 32; }
    else        { A = A2; B = B2; lda = K2; k = k02 + (t - s1) * 32; }
#pragma unroll
    for (int h = 0; h < 2; ++h) {     // A: 512 16B-units
      int U = h * 256 + wid * 64 + lane;
      int m = U >> 2, u = (U & 3) ^ (m & 3);
      GLD16(A + (size_t)(bm + m) * lda + k + u * 8, &As[buf][(h * 256 + wid * 64) * 8]);
    }
#pragma unroll
    for (int h = 0; h < 2; ++h) {     // B: 512 16B-units
      int U = h * 256 + wid * 64 + lane;
      int n = U >> 2, u = (U & 3) ^ (n & 3);
      GLD16(B + (size_t)(bn + n) * lda + k + u * 8, &Bs[buf][(h * 256 + wid * 64) * 8]);
    }
  };

  f32x4 acc[4][4];
#pragma unroll
  for (int mi = 0; mi < 4; ++mi)
#pragma unroll
    for (int ni = 0; ni < 4; ++ni)
#pragma unroll
      for (int r = 0; r < 4; ++r) acc[mi][ni][r] = 0.0f;

  auto COMPUTE = [&](int t) {
    const int cur = t & 3;
    bf16x8 a[4], b[4];
#pragma unroll
    for (int mi = 0; mi < 4; ++mi) {
      int m = wm + mi * 16 + r16;
      a[mi] = __builtin_bit_cast(bf16x8, *(const s16x8*)&As[cur][m * 32 + ((g ^ (m & 3)) << 3)]);
    }
#pragma unroll
    for (int ni = 0; ni < 4; ++ni) {
      int n = wn + ni * 16 + r16;
      b[ni] = __builtin_bit_cast(bf16x8, *(const s16x8*)&Bs[cur][n * 32 + ((g ^ (n & 3)) << 3)]);
    }
    __builtin_amdgcn_s_setprio(1);
#pragma unroll
    for (int mi = 0; mi < 4; ++mi)
#pragma unroll
      for (int ni = 0; ni < 4; ++ni)
        acc[mi][ni] = __builtin_amdgcn_mfma_f32_16x16x32_bf16(a[mi], b[ni], acc[mi][ni], 0, 0, 0);
    __builtin_amdgcn_s_setprio(0);
  };

  STAGE(0, 0);
  STAGE(1, 1);
  STAGE(2, 2);

#pragma unroll 1
  for (int t = 0; t + 2 < total; ++t) {
    WAITVM(8);                          // tile t resident (2 newer in flight)
    __builtin_amdgcn_s_barrier();       // all waves' tile-t loads visible
    __builtin_amdgcn_sched_barrier(0);  // no LDS reads hoisted above barrier
    if (t + 3 < total) STAGE(t + 3, (t + 3) & 3);
    COMPUTE(t);
  }
  WAITVM(4);
  __builtin_amdgcn_s_barrier();
  __builtin_amdgcn_sched_barrier(0);
  COMPUTE(total - 2);
  WAITVM(0);
  __builtin_amdgcn_s_barrier();
  __builtin_amdgcn_sched_barrier(0);
  COMPUTE(total - 1);

#pragma unroll
  for (int mi = 0; mi < 4; ++mi)
#pragma unroll
    for (int r = 0; r < 4; ++r) {
      int row = bm + wm + mi * 16 + g * 4 + r;
#pragma unroll
      for (int ni = 0; ni < 4; ++ni) {
        int col = bn + wn + ni * 16 + r16;
        Pz[(size_t)row * N + col] = acc[mi][ni][r];
      }
    }
}

// ---------------------------------------------------------------------------
// Combine z-partials: sum, optional rscale[row]/bias[col]/relu; write fp32
// plain (may alias P slice 0: same-index read-then-write) and/or bf16 perm.
// ---------------------------------------------------------------------------
__global__ __launch_bounds__(256) void combine_kernel(
    const float* P, int nz, size_t MN,
    const float* rsc, int rshift,
    const float* bias, int cmask, int doRelu,
    short* outb, float* outf)
{
  size_t flat = ((size_t)blockIdx.x * 256 + threadIdx.x) * 4;
  if (flat >= MN) return;
  float4 s = *reinterpret_cast<const float4*>(&P[flat]);
#pragma unroll 1
  for (int zz = 1; zz < nz; ++zz) {
    float4 t = *reinterpret_cast<const float4*>(&P[(size_t)zz * MN + flat]);
    s.x += t.x; s.y += t.y; s.z += t.z; s.w += t.w;
  }
  if (rsc) {
    float sc = rsc[flat >> rshift];
    s.x *= sc; s.y *= sc; s.z *= sc; s.w *= sc;
  }
  if (bias) {
    float4 bv = *reinterpret_cast<const float4*>(&bias[flat & (size_t)cmask]);
    s.x += bv.x; s.y += bv.y; s.z += bv.z; s.w += bv.w;
  }
  if (doRelu) {
    s.x = fmaxf(s.x, 0.0f); s.y = fmaxf(s.y, 0.0f);
    s.z = fmaxf(s.z, 0.0f); s.w = fmaxf(s.w, 0.0f);
  }
  if (outf) *reinterpret_cast<float4*>(&outf[flat]) = s;
  if (outb) {
    s16x4 o;
    o[0] = (short)f2bf(s.x); o[1] = (short)f2bf(s.y);
    o[2] = (short)f2bf(s.z); o[3] = (short)f2bf(s.w);
    size_t base = (flat & ~(size_t)31) | (size_t)pos32((int)(flat & 31));
    *reinterpret_cast<s16x4*>(&outb[base]) = o;
  }
}

// ---------------------------------------------------------------------------
// x1 finisher: sum nz partials + bias + relu, write x1b (bf16, perm cols) AND
// x1T (bf16, transposed, perm slots) via 32x32 LDS tile. Grid (HID/32, N/32).
// ---------------------------------------------------------------------------
__global__ __launch_bounds__(256) void combine_tr_kernel(
    const float* __restrict__ P, int nz,
    const float* __restrict__ bias,
    short* __restrict__ xn, short* __restrict__ xnT)
{
  __shared__ float t[32][33];
  const size_t MN = (size_t)N_NODES * HID;
  int c0 = blockIdx.x * 32, r0 = blockIdx.y * 32;
  int tx = threadIdx.x & 31, ty = threadIdx.x >> 5;
  int colp = c0 + pos32(tx);
#pragma unroll
  for (int i = 0; i < 4; ++i) {
    int row = r0 + ty + 8 * i;
    size_t idx = (size_t)row * HID + c0 + tx;
    float v = P[idx];
#pragma unroll 1
    for (int zz = 1; zz < nz; ++zz) v += P[(size_t)zz * MN + idx];
    v += bias[c0 + tx];
    v = fmaxf(v, 0.0f);
    xn[(size_t)row * HID + colp] = (short)f2bf(v);
    t[ty + 8 * i][tx] = v;
  }
  __syncthreads();
  int ip = pos32(pos32(tx));   // inverse perm
#pragma unroll
  for (int i = 0; i < 4; ++i) {
    int cl = ty + 8 * i;
    xnT[(size_t)(c0 + cl) * N_NODES + r0 + tx] = (short)f2bf(t[ip][cl]);
  }
}

// ---------------------------------------------------------------------------
// Head part 1: per-row scores/rowsum (blocks [0,2048)) and per-col partial
// sums for pooled (blocks [2048,2304)).
// ---------------------------------------------------------------------------
__global__ __launch_bounds__(256) void scores_pooled_kernel(
    const float* __restrict__ x2, const float* __restrict__ Wa,
    const float* __restrict__ ba, float* __restrict__ scores,
    float* __restrict__ rowsum, float* __restrict__ partial)
{
  int bid = blockIdx.x, tid = threadIdx.x;
  if (bid < N_NODES) {
    const float* row = x2 + (size_t)bid * HID;
    float s = 0.0f, r = 0.0f;
    for (int f = tid; f < HID; f += 256) {
      float v = row[f];
      s = fmaf(v, Wa[f], s);
      r += v;
    }
#pragma unroll
    for (int off = 32; off; off >>= 1) {
      s += __shfl_down(s, off);
      r += __shfl_down(r, off);
    }
    __shared__ float sred[4], rred[4];
    if ((tid & 63) == 0) { sred[tid >> 6] = s; rred[tid >> 6] = r; }
    __syncthreads();
    if (tid == 0) {
      scores[bid] = sred[0] + sred[1] + sred[2] + sred[3] + ba[0];
      rowsum[bid] = rred[0] + rred[1] + rred[2] + rred[3];
    }
  } else {
    int q = bid - N_NODES;              // 0..255
    int f  = (q & 7) * 256 + tid;
    int r0 = (q >> 3) * 64;
    float s = 0.0f;
#pragma unroll 4
    for (int r = 0; r < 64; ++r) s += x2[(size_t)(r0 + r) * HID + f];
    partial[(size_t)(q >> 3) * HID + f] = s;
  }
}

// ---------------------------------------------------------------------------
// Head part 2 (single block, 1024 threads): softmax over scores -> ge (LDS),
// pooled from partial (LDS), final linear -> out[16].
// ---------------------------------------------------------------------------
__global__ __launch_bounds__(1024) void tail_kernel(
    const float* __restrict__ scores, const float* __restrict__ rowsum,
    const float* __restrict__ partial,
    const float* __restrict__ Wf, const float* __restrict__ bf,
    float* __restrict__ out)
{
  __shared__ float ge_s[N_NODES];
  __shared__ float pl[HID];
  __shared__ float part[64][NCLS];
  __shared__ float red[16];
  __shared__ float Msh, Zsh;
  int tid = threadIdx.x;

  float m = -1e30f;
  for (int n = tid; n < N_NODES; n += 1024) m = fmaxf(m, scores[n]);
#pragma unroll
  for (int off = 32; off; off >>= 1) m = fmaxf(m, __shfl_down(m, off));
  if ((tid & 63) == 0) red[tid >> 6] = m;
  __syncthreads();
  if (tid == 0) {
    float mm = red[0];
#pragma unroll
    for (int k = 1; k < 16; ++k) mm = fmaxf(mm, red[k]);
    Msh = mm;
  }
  __syncthreads();
  float M = Msh;

  float z = 0.0f;
  for (int n = tid; n < N_NODES; n += 1024) z += expf(scores[n] - M);
#pragma unroll
  for (int off = 32; off; off >>= 1) z += __shfl_down(z, off);
  __syncthreads();
  if ((tid & 63) == 0) red[tid >> 6] = z;
  __syncthreads();
  if (tid == 0) {
    float zz = 0.0f;
#pragma unroll
    for (int k = 0; k < 16; ++k) zz += red[k];
    Zsh = zz;
  }
  __syncthreads();
  float Z = Zsh;

  for (int n = tid; n < N_NODES; n += 1024)
    ge_s[n] = expf(scores[n] - M) / Z * rowsum[n];

  for (int f = tid; f < HID; f += 1024) {
    float s = 0.0f;
#pragma unroll
    for (int r = 0; r < 32; ++r) s += partial[(size_t)r * HID + f];
    pl[f] = s * (1.0f / N_NODES);
  }
  __syncthreads();

  int c = tid & 15, gg = tid >> 4;      // 64 groups of 16 classes
  float s = 0.0f;
  for (int j = gg; j < HID; j += 64) {
    s = fmaf(pl[j],   Wf[(size_t)j * NCLS + c], s);
    s = fmaf(ge_s[j], Wf[(size_t)(HID + j) * NCLS + c], s);
  }
  part[gg][c] = s;
  __syncthreads();
  if (tid < NCLS) {
    float tsum = 0.0f;
#pragma unroll
    for (int k = 0; k < 64; ++k) tsum += part[k][tid];
    out[tid] = tsum + bf[tid];
  }
}

// ---------------------------------------------------------------------------
extern "C" void kernel_launch(void* const* d_in, const int* in_sizes, int n_in,
                              void* d_out, int out_size, void* d_ws, size_t ws_size,
                              hipStream_t stream) {
  const float* x   = (const float*)d_in[0];
  const int*   src = (const int*)  d_in[1];
  const int*   dst = (const int*)  d_in[2];
  const float* W1l = (const float*)d_in[3];
  const float* b1  = (const float*)d_in[4];
  const float* W1r = (const float*)d_in[5];
  const float* W2l = (const float*)d_in[6];
  const float* b2  = (const float*)d_in[7];
  const float* W2r = (const float*)d_in[8];
  const float* Wa  = (const float*)d_in[9];
  const float* ba  = (const float*)d_in[10];
  const float* Wf  = (const float*)d_in[11];
  const float* bf  = (const float*)d_in[12];
  float* out = (float*)d_out;

  const size_t MB = 1u << 20;
  char* w = (char*)d_ws;
  // Lifetime-overlaid layout (~107 MB peak):
  float* P      = (float*)(w);              // 0-64MB: fp32 partials
  float* x2     = (float*)(w);              // alias P slice 0 (in-place combine)
  float* adjf   = (float*)(w + 16 * MB);    // 16-32MB temp; dead before GEMMs
  short* adjb   = (short*)(w + 64 * MB);    // 64-72; dead after mean2
  short* meanb2 = (short*)(w + 64 * MB);    //   overlay (written after mean2)
  short* W2lT   = (short*)(w + 72 * MB);    // 72-80
  short* W2rT   = (short*)(w + 80 * MB);    // 80-88
  short* x1b    = (short*)(w + 88 * MB);    // 88-96
  short* xb     = (short*)(w + 96 * MB);    // 96-98; dead after x1 gemm
  short* xT     = (short*)(w + 98 * MB);    // 98-100
  short* W1lT   = (short*)(w + 100 * MB);   // 100-102
  short* W1rT   = (short*)(w + 102 * MB);   // 102-104
  short* x1T    = (short*)(w + 96 * MB);    //   overlay 96-104 (after x1 gemm)
  short* meanb  = (short*)(w + 104 * MB);   // 104-106; dead after x1 gemm
  float* cnt    = (float*)(w + 106 * MB);
  float* rsc    = cnt    + N_NODES;
  float* scores = rsc    + N_NODES;
  float* rowsum = scores + N_NODES;
  float* partial= rowsum + N_NODES;         // 32*2048

  hipMemsetAsync(adjf, 0, (size_t)N_NODES * N_NODES * sizeof(float), stream);
  hipMemsetAsync(cnt, 0, (size_t)N_NODES * sizeof(float), stream);

  build_adj_kernel<<<E_EDGES / 256, 256, 0, stream>>>(src, dst, adjf, cnt);
  rscale_kernel<<<N_NODES / 256, 256, 0, stream>>>(cnt, rsc);

  prep_kernel<<<16384, 256, 0, stream>>>(adjf, adjb, x, xb, xT,
                                         W1l, W1lT, W1r, W1rT,
                                         W2l, W2lT, W2r, W2rT);

  // mean1 = rowscale(adj @ x): K=2048, nz=8 (512 blocks, 8 steps each)
  gemm_z<<<dim3(IN_DIM / 128, N_NODES / 128, 8), 256, 0, stream>>>(
      adjb, xT, N_NODES, nullptr, nullptr, 0, 8, P, N_NODES, IN_DIM);
  combine_kernel<<<(N_NODES * IN_DIM / 4) / 256, 256, 0, stream>>>(
      P, 8, (size_t)N_NODES * IN_DIM, rsc, 9, nullptr, 0, 0, meanb, nullptr);

  // x1 = relu(mean1 @ W1l + x @ W1r + b1): nz=2 pair-fused (512 blocks, 16 steps)
  gemm_z<<<dim3(HID / 128, N_NODES / 128, 2), 256, 0, stream>>>(
      meanb, W1lT, IN_DIM, xb, W1rT, IN_DIM, 2, P, N_NODES, HID);
  combine_tr_kernel<<<dim3(HID / 32, N_NODES / 32), 256, 0, stream>>>(
      P, 2, b1, x1b, x1T);

  // mean2 = rowscale(adj @ x1): K=2048, nz=2 (512 blocks, 32 steps, P 32MB)
  gemm_z<<<dim3(HID / 128, N_NODES / 128, 2), 256, 0, stream>>>(
      adjb, x1T, N_NODES, nullptr, nullptr, 0, 2, P, N_NODES, HID);
  combine_kernel<<<(N_NODES * HID / 4) / 256, 256, 0, stream>>>(
      P, 2, (size_t)N_NODES * HID, rsc, 11, nullptr, 0, 0, meanb2, nullptr);

  // x2 = relu(mean2 @ W2l + x1 @ W2r + b2): nz=2 pair-fused (512 blocks, 64 steps)
  gemm_z<<<dim3(HID / 128, N_NODES / 128, 2), 256, 0, stream>>>(
      meanb2, W2lT, HID, x1b, W2rT, HID, 2, P, N_NODES, HID);
  combine_kernel<<<(N_NODES * HID / 4) / 256, 256, 0, stream>>>(
      P, 2, (size_t)N_NODES * HID, nullptr, 0, b2, HID - 1, 1, nullptr, x2);

  // head
  scores_pooled_kernel<<<N_NODES + 256, 256, 0, stream>>>(x2, Wa, ba, scores, rowsum, partial);
  tail_kernel<<<1, 1024, 0, stream>>>(scores, rowsum, partial, Wf, bf, out);
}

// Round 7
// 234.453 us; speedup vs baseline: 6.3398x; 1.0152x over previous
//
#include <hip/hip_runtime.h>
#include <hip/hip_bf16.h>
#include <cstddef>
#include <cstdint>

#define N_NODES 2048
#define E_EDGES 131072
#define IN_DIM  512
#define HID     2048
#define NCLS    16

typedef __bf16 bf16x8 __attribute__((ext_vector_type(8)));
typedef short  s16x4  __attribute__((ext_vector_type(4)));
typedef short  s16x8  __attribute__((ext_vector_type(8)));
typedef float  f32x4  __attribute__((ext_vector_type(4)));

__device__ __forceinline__ unsigned short f2bf(float f) {
  unsigned u = __builtin_bit_cast(unsigned, f);
  u = (u + 0x7FFFu + ((u >> 16) & 1u)) >> 16;
  return (unsigned short)u;
}

// K-permutation within each 32-col block: lane g's 8-elem MFMA fragment
// (k = g*4+{0..3}, g*4+16+{0..3}) becomes contiguous slots [8g,8g+8) -> one
// ds_read_b128 per fragment. pos32 is a bit 3-cycle; inverse = pos32 twice.
__device__ __forceinline__ int pos32(int k) {
  return (((k >> 2) & 3) << 3) | (((k >> 4) & 1) << 2) | (k & 3);
}

#define GLD16(gp, lp) __builtin_amdgcn_global_load_lds(                     \
    (__attribute__((address_space(1))) void*)(gp),                          \
    (__attribute__((address_space(3))) void*)(lp), 16, 0, 0)

#define WAITVM(N) asm volatile("s_waitcnt vmcnt(" #N ")" ::: "memory")

// ---------------------------------------------------------------------------
// Dense adjacency build; columns stored K-PERMUTED (perm folded into atomics).
// ---------------------------------------------------------------------------
__global__ void build_adj_kernel(const int* __restrict__ src, const int* __restrict__ dst,
                                 float* __restrict__ adj, float* __restrict__ cnt) {
  int e = blockIdx.x * blockDim.x + threadIdx.x;
  if (e < E_EDGES) {
    int s = src[e], d = dst[e];
    int sp = (s & ~31) | pos32(s & 31);
    atomicAdd(&adj[(size_t)d * N_NODES + sp], 1.0f);
    atomicAdd(&cnt[d], 1.0f);
  }
}

__global__ void rscale_kernel(const float* __restrict__ cnt, float* __restrict__ rscale) {
  int i = blockIdx.x * blockDim.x + threadIdx.x;
  if (i < N_NODES) rscale[i] = 1.0f / fmaxf(cnt[i], 1.0f);
}

// ---------------------------------------------------------------------------
// Fused operand prep: one launch, blockIdx.x ranges select the sub-op.
// ---------------------------------------------------------------------------
__global__ __launch_bounds__(256) void prep_kernel(
    const float* __restrict__ adjf, short* __restrict__ adjb,
    const float* __restrict__ x,   short* __restrict__ xb,   short* __restrict__ xT,
    const float* __restrict__ W1l, short* __restrict__ W1lT,
    const float* __restrict__ W1r, short* __restrict__ W1rT,
    const float* __restrict__ W2l, short* __restrict__ W2lT,
    const float* __restrict__ W2r, short* __restrict__ W2rT)
{
  int bid = blockIdx.x, tid = threadIdx.x;
  if (bid < 4096) {                         // adj cvt (plain layout)
    size_t flat = ((size_t)bid * 256 + tid) * 4;
    float4 v = *reinterpret_cast<const float4*>(&adjf[flat]);
    s16x4 o;
    o[0] = (short)f2bf(v.x); o[1] = (short)f2bf(v.y);
    o[2] = (short)f2bf(v.z); o[3] = (short)f2bf(v.w);
    *reinterpret_cast<s16x4*>(&adjb[flat]) = o;
    return;
  }
  bid -= 4096;
  if (bid < 1024) {                         // x cvt, perm slots
    size_t flat = ((size_t)bid * 256 + tid) * 4;
    float4 v = *reinterpret_cast<const float4*>(&x[flat]);
    s16x4 o;
    o[0] = (short)f2bf(v.x); o[1] = (short)f2bf(v.y);
    o[2] = (short)f2bf(v.z); o[3] = (short)f2bf(v.w);
    size_t base = (flat & ~(size_t)31) | (size_t)pos32((int)(flat & 31));
    *reinterpret_cast<s16x4*>(&xb[base]) = o;
    return;
  }
  bid -= 1024;
  __shared__ float t[32][33];
  const float* in; short* outp; int R, C, bx, by;
  if (bid < 1024)      { in = x;   outp = xT;   R = N_NODES; C = IN_DIM; bx = bid & 15; by = bid >> 4; }
  else if (bid < 2048) { bid -= 1024; in = W1l; outp = W1lT; R = IN_DIM; C = HID; bx = bid & 63; by = bid >> 6; }
  else if (bid < 3072) { bid -= 2048; in = W1r; outp = W1rT; R = IN_DIM; C = HID; bx = bid & 63; by = bid >> 6; }
  else if (bid < 7168) { bid -= 3072; in = W2l; outp = W2lT; R = HID;    C = HID; bx = bid & 63; by = bid >> 6; }
  else                 { bid -= 7168; in = W2r; outp = W2rT; R = HID;    C = HID; bx = bid & 63; by = bid >> 6; }
  int c0 = bx * 32, r0 = by * 32;
  int tx = tid & 31, ty = tid >> 5;
#pragma unroll
  for (int i = 0; i < 4; ++i)
    t[ty + 8 * i][tx] = in[(size_t)(r0 + ty + 8 * i) * C + c0 + tx];
  __syncthreads();
  int ip = pos32(pos32(tx));   // inverse perm
#pragma unroll
  for (int i = 0; i < 4; ++i)
    outp[(size_t)(c0 + ty + 8 * i) * R + r0 + tx] = (short)f2bf(t[ip][ty + 8 * i]);
}

// ---------------------------------------------------------------------------
// 128x128 bf16 MFMA GEMM (4 waves, wave-tile 64x64) for the small layers.
// Bank swizzle: physical unit = logical ^ ((row>>1)&3) -> all 8 16B-slots
// covered evenly per 8-lane group (conflict-free b128 reads).
// ---------------------------------------------------------------------------
__global__ __launch_bounds__(256) void gemm_z(
    const short* __restrict__ A1, const short* __restrict__ B1, int K1,
    const short* __restrict__ A2, const short* __restrict__ B2, int K2,
    int nz, float* __restrict__ P, int M, int N)
{
  __shared__ short As[2][128 * 32];
  __shared__ short Bs[2][128 * 32];

  const int tid = threadIdx.x, wid = tid >> 6, lane = tid & 63;
  const int g = lane >> 4, r16 = lane & 15;
  const int wm = (wid >> 1) * 64, wn = (wid & 1) * 64;
  const int bm = blockIdx.y * 128, bn = blockIdx.x * 128;
  const int z = blockIdx.z;

  const int s1  = K1 / nz / 32;
  const int s2  = A2 ? K2 / nz / 32 : 0;
  const int k01 = z * (K1 / nz);
  const int k02 = A2 ? z * (K2 / nz) : 0;
  const int total = s1 + s2;
  float* Pz = P + (size_t)z * M * N;

  auto STAGE = [&](int t, int buf) {
    const short* A; const short* B; int lda, k;
    if (t < s1) { A = A1; B = B1; lda = K1; k = k01 + t * 32; }
    else        { A = A2; B = B2; lda = K2; k = k02 + (t - s1) * 32; }
#pragma unroll
    for (int h = 0; h < 2; ++h) {
      int U = h * 256 + wid * 64 + lane;
      int m = U >> 2, u = (U & 3) ^ ((m >> 1) & 3);
      GLD16(A + (size_t)(bm + m) * lda + k + u * 8, &As[buf][(h * 256 + wid * 64) * 8]);
    }
#pragma unroll
    for (int h = 0; h < 2; ++h) {
      int U = h * 256 + wid * 64 + lane;
      int n = U >> 2, u = (U & 3) ^ ((n >> 1) & 3);
      GLD16(B + (size_t)(bn + n) * lda + k + u * 8, &Bs[buf][(h * 256 + wid * 64) * 8]);
    }
  };

  f32x4 acc[4][4];
#pragma unroll
  for (int mi = 0; mi < 4; ++mi)
#pragma unroll
    for (int ni = 0; ni < 4; ++ni)
#pragma unroll
      for (int r = 0; r < 4; ++r) acc[mi][ni][r] = 0.0f;

  auto COMPUTE = [&](int t) {
    const int cur = t & 1;
    bf16x8 a[4], b[4];
#pragma unroll
    for (int mi = 0; mi < 4; ++mi) {
      int m = wm + mi * 16 + r16;
      a[mi] = __builtin_bit_cast(bf16x8, *(const s16x8*)&As[cur][m * 32 + ((g ^ ((m >> 1) & 3)) << 3)]);
    }
#pragma unroll
    for (int ni = 0; ni < 4; ++ni) {
      int n = wn + ni * 16 + r16;
      b[ni] = __builtin_bit_cast(bf16x8, *(const s16x8*)&Bs[cur][n * 32 + ((g ^ ((n >> 1) & 3)) << 3)]);
    }
    __builtin_amdgcn_s_setprio(1);
#pragma unroll
    for (int mi = 0; mi < 4; ++mi)
#pragma unroll
      for (int ni = 0; ni < 4; ++ni)
        acc[mi][ni] = __builtin_amdgcn_mfma_f32_16x16x32_bf16(a[mi], b[ni], acc[mi][ni], 0, 0, 0);
    __builtin_amdgcn_s_setprio(0);
  };

  STAGE(0, 0);
  __syncthreads();
#pragma unroll 1
  for (int t = 0; t < total; ++t) {
    if (t + 1 < total) STAGE(t + 1, (t + 1) & 1);
    COMPUTE(t);
    __syncthreads();
  }

#pragma unroll
  for (int mi = 0; mi < 4; ++mi)
#pragma unroll
    for (int r = 0; r < 4; ++r) {
      int row = bm + wm + mi * 16 + g * 4 + r;
#pragma unroll
      for (int ni = 0; ni < 4; ++ni) {
        int col = bn + wn + ni * 16 + r16;
        Pz[(size_t)row * N + col] = acc[mi][ni][r];
      }
    }
}

// ---------------------------------------------------------------------------
// 256x256 bf16 MFMA GEMM, 512 threads = 8 waves (2M x 4N), wave-tile 128x64.
// BK=32; 4-buffer LDS (128 KB) + counted vmcnt(8) pipeline.
// Ledger: prologue stages tiles 0-2 (12 GLD16/thread, order A,B per tile).
// Iter t: WAITVM(8) [issued 12+4t, need 4(t+1) done -> exactly tiles t+1,t+2
// in flight] -> s_barrier -> STAGE_A(t+3) -> Q0 -> STAGE_B(t+3) -> Q1.
// Buffer (t+3)&3 was last read at iter t-1; barrier(t) separates. Peeled
// tails use WAITVM(4)/WAITVM(0). Requires total >= 3 (all call sites >= 16).
// ---------------------------------------------------------------------------
__global__ __launch_bounds__(512) void gemm256(
    const short* __restrict__ A1, const short* __restrict__ B1, int K1,
    const short* __restrict__ A2, const short* __restrict__ B2, int K2,
    int nz, float* __restrict__ P, int M, int N)
{
  __shared__ short As[4][256 * 32];   // 4 x 16 KB
  __shared__ short Bs[4][256 * 32];   // 4 x 16 KB  (128 KB total)

  const int tid = threadIdx.x, wid = tid >> 6, lane = tid & 63;
  const int g = lane >> 4, r16 = lane & 15;
  const int wm = (wid >> 2) * 128, wn = (wid & 3) * 64;
  const int bm = blockIdx.y * 256, bn = blockIdx.x * 256;
  const int z = blockIdx.z;

  const int s1  = K1 / nz / 32;
  const int s2  = A2 ? K2 / nz / 32 : 0;
  const int k01 = z * (K1 / nz);
  const int k02 = A2 ? z * (K2 / nz) : 0;
  const int total = s1 + s2;
  float* Pz = P + (size_t)z * M * N;

  auto SRC = [&](int t, const short*& A, const short*& B, int& lda, int& k) {
    if (t < s1) { A = A1; B = B1; lda = K1; k = k01 + t * 32; }
    else        { A = A2; B = B2; lda = K2; k = k02 + (t - s1) * 32; }
  };
  auto STAGE_A = [&](int t) {
    const short* A; const short* B; int lda, k;
    SRC(t, A, B, lda, k);
    int buf = t & 3;
#pragma unroll
    for (int h = 0; h < 2; ++h) {
      int Pl = h * 512 + tid;               // 0..1023 (16B units)
      int m = Pl >> 2, U = Pl & 3;
      int v = U ^ ((m >> 1) & 3);
      GLD16(A + (size_t)(bm + m) * lda + k + v * 8, &As[buf][(h * 512 + wid * 64) * 8]);
    }
  };
  auto STAGE_B = [&](int t) {
    const short* A; const short* B; int lda, k;
    SRC(t, A, B, lda, k);
    int buf = t & 3;
#pragma unroll
    for (int h = 0; h < 2; ++h) {
      int Pl = h * 512 + tid;
      int n = Pl >> 2, U = Pl & 3;
      int v = U ^ ((n >> 1) & 3);
      GLD16(B + (size_t)(bn + n) * lda + k + v * 8, &Bs[buf][(h * 512 + wid * 64) * 8]);
    }
  };

  f32x4 acc[8][4];
#pragma unroll
  for (int mi = 0; mi < 8; ++mi)
#pragma unroll
    for (int ni = 0; ni < 4; ++ni)
#pragma unroll
      for (int r = 0; r < 4; ++r) acc[mi][ni][r] = 0.0f;

  bf16x8 bfr[4];
  auto QUAD = [&](int buf, int mlo) {
    if (mlo == 0) {
#pragma unroll
      for (int ni = 0; ni < 4; ++ni) {
        int n = wn + ni * 16 + r16;
        bfr[ni] = __builtin_bit_cast(bf16x8, *(const s16x8*)&Bs[buf][n * 32 + ((g ^ ((n >> 1) & 3)) << 3)]);
      }
    }
    bf16x8 a[4];
#pragma unroll
    for (int i = 0; i < 4; ++i) {
      int m = wm + (mlo + i) * 16 + r16;
      a[i] = __builtin_bit_cast(bf16x8, *(const s16x8*)&As[buf][m * 32 + ((g ^ ((m >> 1) & 3)) << 3)]);
    }
    __builtin_amdgcn_s_setprio(1);
#pragma unroll
    for (int i = 0; i < 4; ++i)
#pragma unroll
      for (int ni = 0; ni < 4; ++ni)
        acc[mlo + i][ni] = __builtin_amdgcn_mfma_f32_16x16x32_bf16(a[i], bfr[ni], acc[mlo + i][ni], 0, 0, 0);
    __builtin_amdgcn_s_setprio(0);
  };

  // prologue: tiles 0..2, issue order A,B per tile (vmcnt FIFO = this order)
  STAGE_A(0); STAGE_B(0);
  STAGE_A(1); STAGE_B(1);
  STAGE_A(2); STAGE_B(2);

#pragma unroll 1
  for (int t = 0; t < total - 2; ++t) {
    WAITVM(8);
    __builtin_amdgcn_s_barrier();
    __builtin_amdgcn_sched_barrier(0);
    const int buf = t & 3;
    if (t + 3 < total) STAGE_A(t + 3);
    QUAD(buf, 0);
    if (t + 3 < total) STAGE_B(t + 3);
    QUAD(buf, 4);
  }
  WAITVM(4);
  __builtin_amdgcn_s_barrier();
  __builtin_amdgcn_sched_barrier(0);
  QUAD((total - 2) & 3, 0);
  QUAD((total - 2) & 3, 4);
  WAITVM(0);
  __builtin_amdgcn_s_barrier();
  __builtin_amdgcn_sched_barrier(0);
  QUAD((total - 1) & 3, 0);
  QUAD((total - 1) & 3, 4);

#pragma unroll
  for (int mi = 0; mi < 8; ++mi)
#pragma unroll
    for (int r = 0; r < 4; ++r) {
      int row = bm + wm + mi * 16 + g * 4 + r;
#pragma unroll
      for (int ni = 0; ni < 4; ++ni) {
        int col = bn + wn + ni * 16 + r16;
        Pz[(size_t)row * N + col] = acc[mi][ni][r];
      }
    }
}

// ---------------------------------------------------------------------------
// Combine z-partials: sum, optional rscale[row]/bias[col]/relu; write fp32
// plain (may alias P slice 0: same-index read-then-write) and/or bf16 perm.
// ---------------------------------------------------------------------------
__global__ __launch_bounds__(256) void combine_kernel(
    const float* P, int nz, size_t MN,
    const float* rsc, int rshift,
    const float* bias, int cmask, int doRelu,
    short* outb, float* outf)
{
  size_t flat = ((size_t)blockIdx.x * 256 + threadIdx.x) * 4;
  if (flat >= MN) return;
  float4 s = *reinterpret_cast<const float4*>(&P[flat]);
#pragma unroll 1
  for (int zz = 1; zz < nz; ++zz) {
    float4 t = *reinterpret_cast<const float4*>(&P[(size_t)zz * MN + flat]);
    s.x += t.x; s.y += t.y; s.z += t.z; s.w += t.w;
  }
  if (rsc) {
    float sc = rsc[flat >> rshift];
    s.x *= sc; s.y *= sc; s.z *= sc; s.w *= sc;
  }
  if (bias) {
    float4 bv = *reinterpret_cast<const float4*>(&bias[flat & (size_t)cmask]);
    s.x += bv.x; s.y += bv.y; s.z += bv.z; s.w += bv.w;
  }
  if (doRelu) {
    s.x = fmaxf(s.x, 0.0f); s.y = fmaxf(s.y, 0.0f);
    s.z = fmaxf(s.z, 0.0f); s.w = fmaxf(s.w, 0.0f);
  }
  if (outf) *reinterpret_cast<float4*>(&outf[flat]) = s;
  if (outb) {
    s16x4 o;
    o[0] = (short)f2bf(s.x); o[1] = (short)f2bf(s.y);
    o[2] = (short)f2bf(s.z); o[3] = (short)f2bf(s.w);
    size_t base = (flat & ~(size_t)31) | (size_t)pos32((int)(flat & 31));
    *reinterpret_cast<s16x4*>(&outb[base]) = o;
  }
}

// ---------------------------------------------------------------------------
// x1 finisher: sum nz partials + bias + relu, write x1b (bf16, perm cols) AND
// x1T (bf16, transposed, perm slots) via 32x32 LDS tile. Grid (HID/32, N/32).
// ---------------------------------------------------------------------------
__global__ __launch_bounds__(256) void combine_tr_kernel(
    const float* __restrict__ P, int nz,
    const float* __restrict__ bias,
    short* __restrict__ xn, short* __restrict__ xnT)
{
  __shared__ float t[32][33];
  const size_t MN = (size_t)N_NODES * HID;
  int c0 = blockIdx.x * 32, r0 = blockIdx.y * 32;
  int tx = threadIdx.x & 31, ty = threadIdx.x >> 5;
  int colp = c0 + pos32(tx);
#pragma unroll
  for (int i = 0; i < 4; ++i) {
    int row = r0 + ty + 8 * i;
    size_t idx = (size_t)row * HID + c0 + tx;
    float v = P[idx];
#pragma unroll 1
    for (int zz = 1; zz < nz; ++zz) v += P[(size_t)zz * MN + idx];
    v += bias[c0 + tx];
    v = fmaxf(v, 0.0f);
    xn[(size_t)row * HID + colp] = (short)f2bf(v);
    t[ty + 8 * i][tx] = v;
  }
  __syncthreads();
  int ip = pos32(pos32(tx));   // inverse perm
#pragma unroll
  for (int i = 0; i < 4; ++i) {
    int cl = ty + 8 * i;
    xnT[(size_t)(c0 + cl) * N_NODES + r0 + tx] = (short)f2bf(t[ip][cl]);
  }
}

// ---------------------------------------------------------------------------
// Head part 1: per-row scores/rowsum (blocks [0,2048)) and per-col partial
// sums for pooled (blocks [2048,2304)).
// ---------------------------------------------------------------------------
__global__ __launch_bounds__(256) void scores_pooled_kernel(
    const float* __restrict__ x2, const float* __restrict__ Wa,
    const float* __restrict__ ba, float* __restrict__ scores,
    float* __restrict__ rowsum, float* __restrict__ partial)
{
  int bid = blockIdx.x, tid = threadIdx.x;
  if (bid < N_NODES) {
    const float* row = x2 + (size_t)bid * HID;
    float s = 0.0f, r = 0.0f;
    for (int f = tid; f < HID; f += 256) {
      float v = row[f];
      s = fmaf(v, Wa[f], s);
      r += v;
    }
#pragma unroll
    for (int off = 32; off; off >>= 1) {
      s += __shfl_down(s, off);
      r += __shfl_down(r, off);
    }
    __shared__ float sred[4], rred[4];
    if ((tid & 63) == 0) { sred[tid >> 6] = s; rred[tid >> 6] = r; }
    __syncthreads();
    if (tid == 0) {
      scores[bid] = sred[0] + sred[1] + sred[2] + sred[3] + ba[0];
      rowsum[bid] = rred[0] + rred[1] + rred[2] + rred[3];
    }
  } else {
    int q = bid - N_NODES;              // 0..255
    int f  = (q & 7) * 256 + tid;
    int r0 = (q >> 3) * 64;
    float s = 0.0f;
#pragma unroll 4
    for (int r = 0; r < 64; ++r) s += x2[(size_t)(r0 + r) * HID + f];
    partial[(size_t)(q >> 3) * HID + f] = s;
  }
}

// ---------------------------------------------------------------------------
// Head part 2 (single block, 1024 threads): softmax over scores -> ge (LDS),
// pooled from partial (LDS), final linear -> out[16].
// ---------------------------------------------------------------------------
__global__ __launch_bounds__(1024) void tail_kernel(
    const float* __restrict__ scores, const float* __restrict__ rowsum,
    const float* __restrict__ partial,
    const float* __restrict__ Wf, const float* __restrict__ bf,
    float* __restrict__ out)
{
  __shared__ float ge_s[N_NODES];
  __shared__ float pl[HID];
  __shared__ float part[64][NCLS];
  __shared__ float red[16];
  __shared__ float Msh, Zsh;
  int tid = threadIdx.x;

  float m = -1e30f;
  for (int n = tid; n < N_NODES; n += 1024) m = fmaxf(m, scores[n]);
#pragma unroll
  for (int off = 32; off; off >>= 1) m = fmaxf(m, __shfl_down(m, off));
  if ((tid & 63) == 0) red[tid >> 6] = m;
  __syncthreads();
  if (tid == 0) {
    float mm = red[0];
#pragma unroll
    for (int k = 1; k < 16; ++k) mm = fmaxf(mm, red[k]);
    Msh = mm;
  }
  __syncthreads();
  float M = Msh;

  float z = 0.0f;
  for (int n = tid; n < N_NODES; n += 1024) z += expf(scores[n] - M);
#pragma unroll
  for (int off = 32; off; off >>= 1) z += __shfl_down(z, off);
  __syncthreads();
  if ((tid & 63) == 0) red[tid >> 6] = z;
  __syncthreads();
  if (tid == 0) {
    float zz = 0.0f;
#pragma unroll
    for (int k = 0; k < 16; ++k) zz += red[k];
    Zsh = zz;
  }
  __syncthreads();
  float Z = Zsh;

  for (int n = tid; n < N_NODES; n += 1024)
    ge_s[n] = expf(scores[n] - M) / Z * rowsum[n];

  for (int f = tid; f < HID; f += 1024) {
    float s = 0.0f;
#pragma unroll
    for (int r = 0; r < 32; ++r) s += partial[(size_t)r * HID + f];
    pl[f] = s * (1.0f / N_NODES);
  }
  __syncthreads();

  int c = tid & 15, gg = tid >> 4;      // 64 groups of 16 classes
  float s = 0.0f;
  for (int j = gg; j < HID; j += 64) {
    s = fmaf(pl[j],   Wf[(size_t)j * NCLS + c], s);
    s = fmaf(ge_s[j], Wf[(size_t)(HID + j) * NCLS + c], s);
  }
  part[gg][c] = s;
  __syncthreads();
  if (tid < NCLS) {
    float tsum = 0.0f;
#pragma unroll
    for (int k = 0; k < 64; ++k) tsum += part[k][tid];
    out[tid] = tsum + bf[tid];
  }
}

// ---------------------------------------------------------------------------
extern "C" void kernel_launch(void* const* d_in, const int* in_sizes, int n_in,
                              void* d_out, int out_size, void* d_ws, size_t ws_size,
                              hipStream_t stream) {
  const float* x   = (const float*)d_in[0];
  const int*   src = (const int*)  d_in[1];
  const int*   dst = (const int*)  d_in[2];
  const float* W1l = (const float*)d_in[3];
  const float* b1  = (const float*)d_in[4];
  const float* W1r = (const float*)d_in[5];
  const float* W2l = (const float*)d_in[6];
  const float* b2  = (const float*)d_in[7];
  const float* W2r = (const float*)d_in[8];
  const float* Wa  = (const float*)d_in[9];
  const float* ba  = (const float*)d_in[10];
  const float* Wf  = (const float*)d_in[11];
  const float* bf  = (const float*)d_in[12];
  float* out = (float*)d_out;

  const size_t MB = 1u << 20;
  char* w = (char*)d_ws;
  // Lifetime-overlaid layout (~107 MB peak):
  float* P      = (float*)(w);              // 0-64MB: fp32 partials
  float* x2     = (float*)(w);              // alias P slice 0 (in-place combine)
  float* adjf   = (float*)(w + 16 * MB);    // 16-32MB temp; dead before GEMMs
  short* adjb   = (short*)(w + 64 * MB);    // 64-72; dead after mean2
  short* meanb2 = (short*)(w + 64 * MB);    //   overlay (written after mean2)
  short* W2lT   = (short*)(w + 72 * MB);    // 72-80
  short* W2rT   = (short*)(w + 80 * MB);    // 80-88
  short* x1b    = (short*)(w + 88 * MB);    // 88-96
  short* xb     = (short*)(w + 96 * MB);    // 96-98; dead after x1 gemm
  short* xT     = (short*)(w + 98 * MB);    // 98-100
  short* W1lT   = (short*)(w + 100 * MB);   // 100-102
  short* W1rT   = (short*)(w + 102 * MB);   // 102-104
  short* x1T    = (short*)(w + 96 * MB);    //   overlay 96-104 (after x1 gemm)
  short* meanb  = (short*)(w + 104 * MB);   // 104-106; dead after x1 gemm
  float* cnt    = (float*)(w + 106 * MB);
  float* rsc    = cnt    + N_NODES;
  float* scores = rsc    + N_NODES;
  float* rowsum = scores + N_NODES;
  float* partial= rowsum + N_NODES;         // 32*2048

  hipMemsetAsync(adjf, 0, (size_t)N_NODES * N_NODES * sizeof(float), stream);
  hipMemsetAsync(cnt, 0, (size_t)N_NODES * sizeof(float), stream);

  build_adj_kernel<<<E_EDGES / 256, 256, 0, stream>>>(src, dst, adjf, cnt);
  rscale_kernel<<<N_NODES / 256, 256, 0, stream>>>(cnt, rsc);

  prep_kernel<<<16384, 256, 0, stream>>>(adjf, adjb, x, xb, xT,
                                         W1l, W1lT, W1r, W1rT,
                                         W2l, W2lT, W2r, W2rT);

  // mean1 = rowscale(adj @ x): 128^2 kernel, K=2048, nz=8 (512 blocks)
  gemm_z<<<dim3(IN_DIM / 128, N_NODES / 128, 8), 256, 0, stream>>>(
      adjb, xT, N_NODES, nullptr, nullptr, 0, 8, P, N_NODES, IN_DIM);
  combine_kernel<<<(N_NODES * IN_DIM / 4) / 256, 256, 0, stream>>>(
      P, 8, (size_t)N_NODES * IN_DIM, rsc, 9, nullptr, 0, 0, meanb, nullptr);

  // x1 = relu(mean1 @ W1l + x @ W1r + b1): 128^2 kernel, nz=2 pair-fused
  gemm_z<<<dim3(HID / 128, N_NODES / 128, 2), 256, 0, stream>>>(
      meanb, W1lT, IN_DIM, xb, W1rT, IN_DIM, 2, P, N_NODES, HID);
  combine_tr_kernel<<<dim3(HID / 32, N_NODES / 32), 256, 0, stream>>>(
      P, 2, b1, x1b, x1T);

  // mean2 = rowscale(adj @ x1): 256^2 kernel, nz=4 (256 blocks, 16 K-tiles)
  gemm256<<<dim3(HID / 256, N_NODES / 256, 4), 512, 0, stream>>>(
      adjb, x1T, N_NODES, nullptr, nullptr, 0, 4, P, N_NODES, HID);
  combine_kernel<<<(N_NODES * HID / 4) / 256, 256, 0, stream>>>(
      P, 4, (size_t)N_NODES * HID, rsc, 11, nullptr, 0, 0, meanb2, nullptr);

  // x2 = relu(mean2 @ W2l + x1 @ W2r + b2): 256^2, nz=4 pair-fused (32 K-tiles)
  gemm256<<<dim3(HID / 256, N_NODES / 256, 4), 512, 0, stream>>>(
      meanb2, W2lT, HID, x1b, W2rT, HID, 4, P, N_NODES, HID);
  combine_kernel<<<(N_NODES * HID / 4) / 256, 256, 0, stream>>>(
      P, 4, (size_t)N_NODES * HID, nullptr, 0, b2, HID - 1, 1, nullptr, x2);

  // head
  scores_pooled_kernel<<<N_NODES + 256, 256, 0, stream>>>(x2, Wa, ba, scores, rowsum, partial);
  tail_kernel<<<1, 1024, 0, stream>>>(scores, rowsum, partial, Wf, bf, out);
}